// Round 7
// baseline (1738.038 us; speedup 1.0000x reference)
//
#include <hip/hip_runtime.h>

#define NN 50000
#define NE 1600000
#define NG 512
#define HD 128
#define NGRP 8
#define GRPSZ ((NN + NGRP - 1) / NGRP)   // 6250
#define PCAP 28672                        // per (group,sub) pair capacity (exp ~25K)

typedef __attribute__((ext_vector_type(8))) short bf16x8;
typedef __attribute__((ext_vector_type(4))) float f32x4;

static __device__ __forceinline__ unsigned bf16rn(float x) {
  unsigned b = __float_as_uint(x);
  return (b + 0x7FFFu + ((b >> 16) & 1u)) >> 16;
}
static __device__ __forceinline__ float bf16tof(unsigned short u) {
  return __uint_as_float(((unsigned)u) << 16);
}

// ---------------- edge partition: one sequential read, 64 grouped pair-lists ----------------
__global__ void k_part(const int* __restrict__ src, const int* __restrict__ dst,
                       uint2* __restrict__ pairs, int* __restrict__ pcnt) {
  const int lane = threadIdx.x & 63;
  const int b = blockIdx.x & 7;
  int gw = blockIdx.x * 4 + (threadIdx.x >> 6);
  int nw = gridDim.x * 4;
  for (int t = gw * 64; t < NE; t += nw * 64) {
    int e = t + lane;
    bool valid = e < NE;
    int d = valid ? dst[e] : 0;
    int s = valid ? src[e] : 0;
    int g = d / GRPSZ;
#pragma unroll
    for (int g0 = 0; g0 < 8; ++g0) {
      bool pred = valid && (g == g0);
      unsigned long long mask = __ballot(pred);
      if (mask == 0ull) continue;                 // wave-uniform
      int cnt = __popcll(mask);
      int leader = __ffsll((unsigned long long)mask) - 1;
      int base = 0;
      if (lane == leader) base = atomicAdd(&pcnt[g0 * 8 + b], cnt);
      base = __shfl(base, leader);
      if (pred) {
        int rank = __popcll(mask & ((1ull << lane) - 1ull));
        int pos = base + rank;
        if (pos < PCAP)
          pairs[(size_t)(g0 * 8 + b) * PCAP + pos] = make_uint2((unsigned)d, (unsigned)s);
      }
    }
  }
}

// ---------------- degree count from grouped pairs (XCD-local atomics) ----------------
__global__ void k_deg2(const uint2* __restrict__ pairs, const int* __restrict__ pcnt,
                       int* __restrict__ deg) {
  int g = blockIdx.x & 7;
  int bi = blockIdx.x >> 3;
  int nb = gridDim.x >> 3;
  for (int sub = 0; sub < 8; ++sub) {
    int cnt = min(pcnt[g * 8 + sub], PCAP);
    const uint2* lst = pairs + (size_t)(g * 8 + sub) * PCAP;
    for (int i = bi * 256 + (int)threadIdx.x; i < cnt; i += nb * 256)
      atomicAdd(&deg[lst[i].x], 1);
  }
}

// ---------------- scatter from grouped pairs ----------------
__global__ void k_scat2(const uint2* __restrict__ pairs, const int* __restrict__ pcnt,
                        int* __restrict__ cursor, int* __restrict__ csr_src) {
  int g = blockIdx.x & 7;
  int bi = blockIdx.x >> 3;
  int nb = gridDim.x >> 3;
  for (int sub = 0; sub < 8; ++sub) {
    int cnt = min(pcnt[g * 8 + sub], PCAP);
    const uint2* lst = pairs + (size_t)(g * 8 + sub) * PCAP;
    for (int i = bi * 256 + (int)threadIdx.x; i < cnt; i += nb * 256) {
      uint2 p = lst[i];
      int pos = atomicAdd(&cursor[p.x], 1);
      csr_src[pos] = (int)p.y;
    }
  }
}

__global__ void k_scan_block(const int* __restrict__ in, int* __restrict__ out,
                             int* __restrict__ bsum, int n) {
  __shared__ int tmp[1024];
  int i = blockIdx.x * 1024 + threadIdx.x;
  int v = (i < n) ? in[i] : 0;
  tmp[threadIdx.x] = v;
  __syncthreads();
  for (int off = 1; off < 1024; off <<= 1) {
    int t = (threadIdx.x >= (unsigned)off) ? tmp[threadIdx.x - off] : 0;
    __syncthreads();
    tmp[threadIdx.x] += t;
    __syncthreads();
  }
  if (i < n) out[i] = tmp[threadIdx.x] - v;   // exclusive
  if (threadIdx.x == 1023 && bsum) bsum[blockIdx.x] = tmp[1023];
}

__global__ void k_scan_small(int* __restrict__ a, int n) {
  __shared__ int tmp[1024];
  int v = ((int)threadIdx.x < n) ? a[threadIdx.x] : 0;
  tmp[threadIdx.x] = v;
  __syncthreads();
  for (int off = 1; off < 1024; off <<= 1) {
    int t = (threadIdx.x >= (unsigned)off) ? tmp[threadIdx.x - off] : 0;
    __syncthreads();
    tmp[threadIdx.x] += t;
    __syncthreads();
  }
  if ((int)threadIdx.x < n) a[threadIdx.x] = tmp[threadIdx.x] - v;
}

__global__ void k_scan_add(int* __restrict__ out, const int* __restrict__ bsum, int n) {
  int i = blockIdx.x * 1024 + threadIdx.x;
  if (i < n) out[i] += bsum[blockIdx.x];
  if (blockIdx.x == 0 && threadIdx.x == 0) out[n] = NE;  // row_ptr[N] = E
}

__global__ void k_copy_int(const int* __restrict__ a, int* __restrict__ b, int n) {
  int i = blockIdx.x * 256 + threadIdx.x;
  if (i < n) b[i] = a[i];
}

// ---------------- graph segment bounds (batch is sorted) ----------------
__global__ void k_init_bounds(int* __restrict__ gs, int* __restrict__ ge) {
  int g = blockIdx.x * 256 + threadIdx.x;
  if (g < NG) { gs[g] = NN; ge[g] = 0; }
}
__global__ void k_bounds(const int* __restrict__ batch, int* __restrict__ gs, int* __restrict__ ge) {
  int n = blockIdx.x * 256 + threadIdx.x;
  if (n < NN) {
    int b = batch[n];
    atomicMin(&gs[b], n);
    atomicMax(&ge[b], n + 1);
  }
}

// ---------------- fp32 -> bf16 convert ----------------
__global__ void k_cvt(const float* __restrict__ a, unsigned short* __restrict__ b, int n) {
  int i = blockIdx.x * 256 + threadIdx.x;
  if (i < n) b[i] = (unsigned short)bf16rn(a[i]);
}

// ---------------- GAT softmax + aggregate (bf16 in, bf16 out) ----------------
__global__ void k_gat_agg(const unsigned* __restrict__ nf16, const float* __restrict__ e1,
                          const int* __restrict__ row_ptr, const int* __restrict__ csr_src,
                          unsigned short* __restrict__ agg16) {
  int node = blockIdx.x * 4 + (threadIdx.x >> 6);
  int lane = threadIdx.x & 63;
  if (node >= NN) return;
  int s = row_ptr[node], e = row_ptr[node + 1];
  const int q = lane >> 4;
  const int c = lane & 15;

  float acc[8];
#pragma unroll
  for (int i = 0; i < 8; ++i) acc[i] = 0.f;
  float zloc = 0.f;

  int jj = s + q;
  bool v0 = jj < e;
  int sc = v0 ? csr_src[jj] : 0;
  float w = v0 ? e1[sc] : 0.f;
  uint4 u = *(const uint4*)(nf16 + (size_t)sc * 64 + c * 4);

  for (int j = s; j < e; j += 4) {
    int jn = j + 4 + q;
    bool vn = jn < e;
    int scn = vn ? csr_src[jn] : 0;
    float wn = vn ? e1[scn] : 0.f;
    uint4 un = *(const uint4*)(nf16 + (size_t)scn * 64 + c * 4);
    zloc += w;
    acc[0] = fmaf(w, __uint_as_float(u.x << 16), acc[0]);
    acc[1] = fmaf(w, __uint_as_float(u.x & 0xFFFF0000u), acc[1]);
    acc[2] = fmaf(w, __uint_as_float(u.y << 16), acc[2]);
    acc[3] = fmaf(w, __uint_as_float(u.y & 0xFFFF0000u), acc[3]);
    acc[4] = fmaf(w, __uint_as_float(u.z << 16), acc[4]);
    acc[5] = fmaf(w, __uint_as_float(u.z & 0xFFFF0000u), acc[5]);
    acc[6] = fmaf(w, __uint_as_float(u.w << 16), acc[6]);
    acc[7] = fmaf(w, __uint_as_float(u.w & 0xFFFF0000u), acc[7]);
    sc = scn; w = wn; u = un;
  }

  zloc += __shfl_xor(zloc, 16);
  zloc += __shfl_xor(zloc, 32);
  float inv = (zloc > 0.f) ? 1.f / zloc : 0.f;
#pragma unroll
  for (int i = 0; i < 8; ++i) {
    acc[i] += __shfl_xor(acc[i], 16);
    acc[i] += __shfl_xor(acc[i], 32);
    acc[i] *= inv;
  }
  if (q == 0) {
    uint4 pk;
    pk.x = bf16rn(acc[0]) | (bf16rn(acc[1]) << 16);
    pk.y = bf16rn(acc[2]) | (bf16rn(acc[3]) << 16);
    pk.z = bf16rn(acc[4]) | (bf16rn(acc[5]) << 16);
    pk.w = bf16rn(acc[6]) | (bf16rn(acc[7]) << 16);
    *(uint4*)(agg16 + (size_t)node * HD + c * 8) = pk;
  }
}

// ---------------- MFMA bf16 GEMM (direct-from-global fragments) ----------------
template <int K, int KA, int HO, bool RELUOUT, bool BIAS, bool OUTF32, bool OUT16, int DOTM>
__global__ void __launch_bounds__(256) k_mfma(
    const unsigned short* __restrict__ A1, const unsigned short* __restrict__ A2,
    const unsigned short* __restrict__ W16, const float* __restrict__ bias,
    float* __restrict__ outf, unsigned short* __restrict__ out16,
    const float* __restrict__ dvec, float* __restrict__ dout, int nrows) {
  constexpr int NT = HO / 16;
  const int l = threadIdx.x & 63;
  const int w = threadIdx.x >> 6;
  const int lr = l & 15;
  const int q = l >> 4;
  const int row0 = blockIdx.x * 64 + w * 16;
  const int arow = min(row0 + lr, nrows - 1);
  const unsigned short* pa1 = A1 + (size_t)arow * KA;
  const unsigned short* pa2 = (KA < K) ? (A2 + (size_t)arow * (K - KA)) : nullptr;

  f32x4 acc[NT];
#pragma unroll
  for (int t = 0; t < NT; ++t) acc[t] = (f32x4){0.f, 0.f, 0.f, 0.f};

#pragma unroll
  for (int s = 0; s < K / 32; ++s) {
    const int kg = s * 32 + q * 8;
    bf16x8 af;
    if constexpr (KA == K) {
      af = *(const bf16x8*)(pa1 + kg);
    } else {
      af = (s * 32 < KA) ? *(const bf16x8*)(pa1 + kg)
                         : *(const bf16x8*)(pa2 + (kg - KA));
    }
#pragma unroll
    for (int t = 0; t < NT; ++t) {
      bf16x8 bfr = *(const bf16x8*)(W16 + (size_t)(t * 16 + lr) * K + kg);
      acc[t] = __builtin_amdgcn_mfma_f32_16x16x32_bf16(af, bfr, acc[t], 0, 0, 0);
    }
  }

  float bv[BIAS ? NT : 1];
  if constexpr (BIAS) {
#pragma unroll
    for (int t = 0; t < NT; ++t) bv[t] = bias[t * 16 + lr];
  }
  float dv[DOTM == 1 ? NT : 1];
  if constexpr (DOTM == 1) {
#pragma unroll
    for (int t = 0; t < NT; ++t) dv[t] = dvec[t * 16 + lr];
  }
  float p[4] = {0.f, 0.f, 0.f, 0.f};
#pragma unroll
  for (int j = 0; j < 4; ++j) {
    int n = row0 + q * 4 + j;
    bool ok = n < nrows;
#pragma unroll
    for (int t = 0; t < NT; ++t) {
      float v = acc[t][j];
      if constexpr (BIAS) v += bv[t];
      if constexpr (RELUOUT) v = fmaxf(v, 0.f);
      if (ok) {
        if constexpr (OUTF32) outf[(size_t)n * HO + t * 16 + lr] = v;
        if constexpr (OUT16) out16[(size_t)n * HO + t * 16 + lr] = (unsigned short)bf16rn(v);
      }
      if constexpr (DOTM == 1) p[j] = fmaf(v, dv[t], p[j]);
      if constexpr (DOTM == 2) p[j] = fmaf(v, v, p[j]);
    }
  }
  if constexpr (DOTM != 0) {
#pragma unroll
    for (int j = 0; j < 4; ++j) {
      p[j] += __shfl_xor(p[j], 1);
      p[j] += __shfl_xor(p[j], 2);
      p[j] += __shfl_xor(p[j], 4);
      p[j] += __shfl_xor(p[j], 8);
    }
    if (lr == 0) {
#pragma unroll
      for (int j = 0; j < 4; ++j) {
        int n = row0 + q * 4 + j;
        if (n < nrows) dout[n] = (DOTM == 1) ? __expf(p[j]) : p[j];
      }
    }
  }
}

// ---------------- fp32 register-tiled GEMM (input + gf head) ----------------
template <int K, int KA, int HO, bool PRE, bool RELUOUT, bool BIAS, bool OUT16, int DOTM>
__global__ void __launch_bounds__(256) k_gemm(
    const float* __restrict__ inA, const float* __restrict__ inB,
    const float* __restrict__ W, const float* __restrict__ bias,
    const float* __restrict__ preA, const float* __restrict__ preB,
    float* __restrict__ out, int nrows,
    unsigned* __restrict__ out16, const float* __restrict__ dvec,
    float* __restrict__ dout) {
  constexpr int KC = 64;
  constexpr int BM = 64;
  constexpr int MT = 4;
  constexpr int NT = HO / 16;
  constexpr int LDW = HO + 4;
  constexpr int LDA = KC + 4;

  __shared__ float Wl[KC * LDW];
  __shared__ float inl[BM * LDA];

  const int tid = threadIdx.x;
  const int tr = tid >> 4;
  const int tc = tid & 15;
  const int row0 = blockIdx.x * BM;
  const int r0 = tr * MT;
  const int c0 = tc * NT;

  float acc[MT][NT];
#pragma unroll
  for (int i = 0; i < MT; ++i)
#pragma unroll
    for (int j = 0; j < NT; ++j) acc[i][j] = BIAS ? bias[c0 + j] : 0.f;

  for (int cc = 0; cc < K / KC; ++cc) {
    const int k0 = cc * KC;
    if (cc) __syncthreads();
    for (int idx = tid; idx < HO * (KC / 4); idx += 256) {
      int h = idx >> 4;
      int qq = idx & 15;
      float4 w = *(const float4*)(W + (size_t)h * K + k0 + qq * 4);
      Wl[(qq * 4 + 0) * LDW + h] = w.x;
      Wl[(qq * 4 + 1) * LDW + h] = w.y;
      Wl[(qq * 4 + 2) * LDW + h] = w.z;
      Wl[(qq * 4 + 3) * LDW + h] = w.w;
    }
    for (int idx = tid; idx < BM * (KC / 4); idx += 256) {
      int r = idx >> 4;
      int qq = idx & 15;
      int n = row0 + r;
      int kg = k0 + qq * 4;
      float4 v = make_float4(0.f, 0.f, 0.f, 0.f);
      if (n < nrows) {
        if constexpr (KA == K) {
          v = *(const float4*)(inA + (size_t)n * K + kg);
        } else {
          if (k0 < KA) v = *(const float4*)(inA + (size_t)n * KA + kg);
          else         v = *(const float4*)(inB + (size_t)n * (K - KA) + kg - KA);
        }
      }
      if constexpr (PRE) {
        v.x = fmaxf(v.x * preA[kg + 0] + preB[kg + 0], 0.f);
        v.y = fmaxf(v.y * preA[kg + 1] + preB[kg + 1], 0.f);
        v.z = fmaxf(v.z * preA[kg + 2] + preB[kg + 2], 0.f);
        v.w = fmaxf(v.w * preA[kg + 3] + preB[kg + 3], 0.f);
      }
      *(float4*)(inl + r * LDA + qq * 4) = v;
    }
    __syncthreads();
#pragma unroll 8
    for (int k = 0; k < KC; ++k) {
      float a[MT];
#pragma unroll
      for (int i = 0; i < MT; ++i) a[i] = inl[(r0 + i) * LDA + k];
      float4 b0 = *(const float4*)(Wl + k * LDW + c0);
#pragma unroll
      for (int i = 0; i < MT; ++i) {
        acc[i][0] = fmaf(a[i], b0.x, acc[i][0]);
        acc[i][1] = fmaf(a[i], b0.y, acc[i][1]);
        acc[i][2] = fmaf(a[i], b0.z, acc[i][2]);
        acc[i][3] = fmaf(a[i], b0.w, acc[i][3]);
      }
      if constexpr (NT == 8) {
        float4 b1 = *(const float4*)(Wl + k * LDW + c0 + 4);
#pragma unroll
        for (int i = 0; i < MT; ++i) {
          acc[i][4] = fmaf(a[i], b1.x, acc[i][4]);
          acc[i][5] = fmaf(a[i], b1.y, acc[i][5]);
          acc[i][6] = fmaf(a[i], b1.z, acc[i][6]);
          acc[i][7] = fmaf(a[i], b1.w, acc[i][7]);
        }
      }
    }
  }
  float dv[DOTM == 1 ? NT : 1];
  if constexpr (DOTM == 1) {
#pragma unroll
    for (int j = 0; j < NT; ++j) dv[j] = dvec[c0 + j];
  }
#pragma unroll
  for (int i = 0; i < MT; ++i) {
    int n = row0 + r0 + i;
    if constexpr (RELUOUT) {
#pragma unroll
      for (int j = 0; j < NT; ++j) acc[i][j] = fmaxf(acc[i][j], 0.f);
    }
    if (n < nrows) {
      float4 o0 = make_float4(acc[i][0], acc[i][1], acc[i][2], acc[i][3]);
      *(float4*)(out + (size_t)n * HO + c0) = o0;
      if constexpr (NT == 8) {
        float4 o1 = make_float4(acc[i][4], acc[i][5], acc[i][6], acc[i][7]);
        *(float4*)(out + (size_t)n * HO + c0 + 4) = o1;
      }
      if constexpr (OUT16 && NT == 8) {
        uint4 pk;
        pk.x = bf16rn(acc[i][0]) | (bf16rn(acc[i][1]) << 16);
        pk.y = bf16rn(acc[i][2]) | (bf16rn(acc[i][3]) << 16);
        pk.z = bf16rn(acc[i][4]) | (bf16rn(acc[i][5]) << 16);
        pk.w = bf16rn(acc[i][6]) | (bf16rn(acc[i][7]) << 16);
        *(uint4*)(out16 + (size_t)n * 64 + tc * 4) = pk;
      }
    }
    if constexpr (DOTM != 0) {
      float p = 0.f;
#pragma unroll
      for (int j = 0; j < NT; ++j)
        p = fmaf(acc[i][j], (DOTM == 1) ? dv[j] : acc[i][j], p);
      p += __shfl_xor(p, 1);
      p += __shfl_xor(p, 2);
      p += __shfl_xor(p, 4);
      p += __shfl_xor(p, 8);
      if (tc == 0 && n < nrows) dout[n] = (DOTM == 1) ? __expf(p) : p;
    }
  }
}

// ---------------- attention pooling (block per graph; nf in bf16) ----------------
__global__ void k_pool(const unsigned short* __restrict__ nf16, const float* __restrict__ r,
                       const int* __restrict__ gs, const int* __restrict__ ge,
                       float* __restrict__ alpha, float* __restrict__ gf) {
  int g = blockIdx.x;
  int s = gs[g], e = ge[g];
  __shared__ float red[256];
  for (int it = 0; it < 3; ++it) {
    float lm = -INFINITY;
    for (int n = s + threadIdx.x; n < e; n += 256) {
      float l = r[n];
      if (it) l *= alpha[n];
      lm = fmaxf(lm, l);
    }
    red[threadIdx.x] = lm;
    __syncthreads();
    for (int off = 128; off > 0; off >>= 1) {
      if ((int)threadIdx.x < off) red[threadIdx.x] = fmaxf(red[threadIdx.x], red[threadIdx.x + off]);
      __syncthreads();
    }
    float m = red[0];
    __syncthreads();
    float zz = 0.f;
    for (int n = s + threadIdx.x; n < e; n += 256) {
      float l = r[n];
      if (it) l *= alpha[n];
      zz += __expf(l - m);
    }
    red[threadIdx.x] = zz;
    __syncthreads();
    for (int off = 128; off > 0; off >>= 1) {
      if ((int)threadIdx.x < off) red[threadIdx.x] += red[threadIdx.x + off];
      __syncthreads();
    }
    float z = red[0];
    __syncthreads();
    float invz = 1.f / z;
    for (int n = s + threadIdx.x; n < e; n += 256) {
      float l = r[n];
      if (it) l *= alpha[n];
      alpha[n] = __expf(l - m) * invz;
    }
    __syncthreads();
  }
  int c = threadIdx.x & 127;
  int rr2 = threadIdx.x >> 7;
  float acc = 0.f;
  for (int n = s + rr2; n < e; n += 2)
    acc += alpha[n] * bf16tof(nf16[(size_t)n * HD + c]);
  red[threadIdx.x] = acc;
  __syncthreads();
  if (rr2 == 0) gf[(size_t)g * HD + c] = red[threadIdx.x] + red[threadIdx.x + 128];
}

// ---------------- BN stats / apply ----------------
__global__ void k_colstats(const float* __restrict__ y, float* __restrict__ sum,
                           float* __restrict__ sumsq, int R, int CH) {
  int c = threadIdx.x & 127;
  int rr = threadIdx.x >> 7;
  int r0 = blockIdx.x * CH;
  int r1 = min(R, r0 + CH);
  float s = 0.f, q = 0.f;
  for (int r = r0 + rr; r < r1; r += 2) {
    float v = y[(size_t)r * HD + c];
    s += v;
    q += v * v;
  }
  __shared__ float ls[256], lq[256];
  ls[threadIdx.x] = s;
  lq[threadIdx.x] = q;
  __syncthreads();
  if (rr == 0) {
    s += ls[threadIdx.x + 128];
    q += lq[threadIdx.x + 128];
    atomicAdd(&sum[c], s);
    atomicAdd(&sumsq[c], q);
  }
}

__global__ void k_bn_final(const float* __restrict__ sum, const float* __restrict__ sumsq,
                           const float* __restrict__ g, const float* __restrict__ b,
                           float* __restrict__ A, float* __restrict__ B, float R) {
  int c = threadIdx.x;
  float mu = sum[c] / R;
  float var = sumsq[c] / R - mu * mu;
  float a = g[c] * rsqrtf(var + 1e-5f);
  A[c] = a;
  B[c] = b[c] - mu * a;
}

// z16 = bf16(relu(A*y+B)) elementwise over [NN][128]
__global__ void k_bnapply(const float* __restrict__ y, const float* __restrict__ Ac,
                          const float* __restrict__ Bc, unsigned short* __restrict__ z) {
  int i = blockIdx.x * 256 + threadIdx.x;
  if (i >= NN * 16) return;
  int c = (i & 15) * 8;
  const float4* yp = (const float4*)y + (size_t)i * 2;
  float4 v0 = yp[0], v1 = yp[1];
  float4 a0 = *(const float4*)(Ac + c), a1 = *(const float4*)(Ac + c + 4);
  float4 b0 = *(const float4*)(Bc + c), b1 = *(const float4*)(Bc + c + 4);
  float r0 = fmaxf(fmaf(v0.x, a0.x, b0.x), 0.f);
  float r1 = fmaxf(fmaf(v0.y, a0.y, b0.y), 0.f);
  float r2 = fmaxf(fmaf(v0.z, a0.z, b0.z), 0.f);
  float r3 = fmaxf(fmaf(v0.w, a0.w, b0.w), 0.f);
  float r4 = fmaxf(fmaf(v1.x, a1.x, b1.x), 0.f);
  float r5 = fmaxf(fmaf(v1.y, a1.y, b1.y), 0.f);
  float r6 = fmaxf(fmaf(v1.z, a1.z, b1.z), 0.f);
  float r7 = fmaxf(fmaf(v1.w, a1.w, b1.w), 0.f);
  uint4 pk;
  pk.x = bf16rn(r0) | (bf16rn(r1) << 16);
  pk.y = bf16rn(r2) | (bf16rn(r3) << 16);
  pk.z = bf16rn(r4) | (bf16rn(r5) << 16);
  pk.w = bf16rn(r6) | (bf16rn(r7) << 16);
  *(uint4*)(z + (size_t)i * 8) = pk;
}

__global__ void k_copy4(const float4* __restrict__ a, float4* __restrict__ b, int n) {
  int i = blockIdx.x * 256 + threadIdx.x;
  if (i < n) b[i] = a[i];
}

extern "C" void kernel_launch(void* const* d_in, const int* in_sizes, int n_in,
                              void* d_out, int out_size, void* d_ws, size_t ws_size,
                              hipStream_t stream) {
  const float* x        = (const float*)d_in[0];
  const int*   ei       = (const int*)d_in[1];
  const float* edge_attr= (const float*)d_in[2];
  const int*   batch    = (const int*)d_in[3];
  const float* Wi       = (const float*)d_in[5];
  const float* bi       = (const float*)d_in[6];
  const float* gat_W    = (const float*)d_in[7];
  const float* gat_a    = (const float*)d_in[8];
  const float* nfW1     = (const float*)d_in[9];
  const float* nfb1     = (const float*)d_in[10];
  const float* nf_g     = (const float*)d_in[11];
  const float* nf_b     = (const float*)d_in[12];
  const float* nfW2     = (const float*)d_in[13];
  const float* nfb2     = (const float*)d_in[14];
  const float* gfW1     = (const float*)d_in[15];
  const float* gfb1     = (const float*)d_in[16];
  const float* gf_g     = (const float*)d_in[17];
  const float* gf_b     = (const float*)d_in[18];
  const float* gfW2     = (const float*)d_in[19];
  const float* gfb2     = (const float*)d_in[20];

  float* out = (float*)d_out;

  unsigned short* nf16A = (unsigned short*)d_ws;          // NN*128
  unsigned short* nf16B = nf16A + (size_t)NN * HD;
  unsigned short* agg16 = nf16B + (size_t)NN * HD;
  unsigned short* z16   = agg16 + (size_t)NN * HD;
  unsigned short* wt_gat = z16 + (size_t)NN * HD;          // 3*128*256
  unsigned short* wt_nf1 = wt_gat + 3 * 128 * 256;         // 128*128
  unsigned short* wt_nf2 = wt_nf1 + 128 * 128;             // 64*128
  float* nfA   = (float*)(wt_nf2 + 64 * 128);              // [NN][128] (y scratch)
  float* e1v   = nfA + (size_t)NN * HD;
  float* rv    = e1v + NN;
  float* alpha = rv + NN;
  float* gf    = alpha + NN;
  float* gy    = gf + (size_t)NG * HD;
  float* sums  = gy + (size_t)NG * HD;   // 512: sum,sumsq,A,B
  int* deg     = (int*)(sums + 512);
  int* row_ptr = deg + NN;
  int* cursor  = row_ptr + NN + 1;
  int* csr_src = cursor + NN;
  int* bsum    = csr_src + NE;
  int* gs      = bsum + 64;
  int* ge      = gs + NG;
  int* pcnt    = ge + NG;                // 64 counters
  // pair lists alias nfA scratch (used strictly before nfA is written)
  uint2* pairs = (uint2*)nfA;            // 64 * PCAP * 8B = 14.7MB < 25.6MB

  const int* src  = ei;
  const int* dstp = ei + NE;

  // ---- CSR by dst: partition-once, then XCD-local count & scatter ----
  hipMemsetAsync(deg, 0, NN * sizeof(int), stream);
  hipMemsetAsync(pcnt, 0, 64 * sizeof(int), stream);
  k_part<<<2048, 256, 0, stream>>>(src, dstp, pairs, pcnt);
  k_deg2<<<2048, 256, 0, stream>>>(pairs, pcnt, deg);
  int nsb = (NN + 1023) / 1024;
  k_scan_block<<<nsb, 1024, 0, stream>>>(deg, row_ptr, bsum, NN);
  k_scan_small<<<1, 1024, 0, stream>>>(bsum, nsb);
  k_scan_add<<<nsb, 1024, 0, stream>>>(row_ptr, bsum, NN);
  k_copy_int<<<(NN + 255) / 256, 256, 0, stream>>>(row_ptr, cursor, NN);
  k_scat2<<<2048, 256, 0, stream>>>(pairs, pcnt, cursor, csr_src);

  // ---- graph bounds ----
  k_init_bounds<<<2, 256, 0, stream>>>(gs, ge);
  k_bounds<<<(NN + 255) / 256, 256, 0, stream>>>(batch, gs, ge);

  // ---- weights -> bf16 ----
  k_cvt<<<(3 * 128 * 256 + 255) / 256, 256, 0, stream>>>(gat_W, wt_gat, 3 * 128 * 256);
  k_cvt<<<(128 * 128 + 255) / 256, 256, 0, stream>>>(nfW1, wt_nf1, 128 * 128);
  k_cvt<<<(64 * 128 + 255) / 256, 256, 0, stream>>>(nfW2, wt_nf2, 64 * 128);

  // ---- input linear (fp32): nf16A + e1 = exp(nf . a0) ----
  k_gemm<64, 64, 128, false, false, true, true, 1><<<(NN + 63) / 64, 256, 0, stream>>>(
      x, nullptr, Wi, bi, nullptr, nullptr, nfA, NN, (unsigned*)nf16A, gat_a, e1v);

  // ---- 3 GAT layers (MFMA) ----
  unsigned short* cur = nf16A;
  unsigned short* nxt = nf16B;
  const int gemm_grid = (NN + 63) / 64;
  for (int l = 0; l < 3; ++l) {
    k_gat_agg<<<(NN + 3) / 4, 256, 0, stream>>>((const unsigned*)cur, e1v, row_ptr, csr_src, agg16);
    if (l < 2) {
      k_mfma<256, 128, 128, true, false, false, true, 1><<<gemm_grid, 256, 0, stream>>>(
          cur, agg16, wt_gat + (size_t)l * 128 * 256, nullptr,
          nullptr, nxt, gat_a + (size_t)(l + 1) * 256, e1v, NN);
    } else {
      k_mfma<256, 128, 128, true, false, false, true, 2><<<gemm_grid, 256, 0, stream>>>(
          cur, agg16, wt_gat + (size_t)l * 128 * 256, nullptr,
          nullptr, nxt, nullptr, rv, NN);
    }
    unsigned short* t = cur; cur = nxt; nxt = t;
  }

  // ---- attention pooling ----
  k_pool<<<NG, 256, 0, stream>>>(cur, rv, gs, ge, alpha, gf);

  // ---- nf head ----
  k_mfma<128, 128, 128, false, true, true, false, 0><<<gemm_grid, 256, 0, stream>>>(
      cur, nullptr, wt_nf1, nfb1, nfA, nullptr, nullptr, nullptr, NN);
  hipMemsetAsync(sums, 0, 256 * sizeof(float), stream);
  k_colstats<<<200, 256, 0, stream>>>(nfA, sums, sums + 128, NN, 250);
  k_bn_final<<<1, 128, 0, stream>>>(sums, sums + 128, nf_g, nf_b, sums + 256, sums + 384, (float)NN);
  k_bnapply<<<(NN * 16 + 255) / 256, 256, 0, stream>>>(nfA, sums + 256, sums + 384, z16);
  k_mfma<128, 128, 64, false, true, true, false, 0><<<gemm_grid, 256, 0, stream>>>(
      z16, nullptr, wt_nf2, nfb2, out, nullptr, nullptr, nullptr, NN);

  // ---- gf head (fp32, tiny) ----
  k_gemm<128, 128, 128, false, false, true, false, 0><<<(NG + 63) / 64, 256, 0, stream>>>(
      gf, nullptr, gfW1, gfb1, nullptr, nullptr, gy, NG, nullptr, nullptr, nullptr);
  hipMemsetAsync(sums, 0, 256 * sizeof(float), stream);
  k_colstats<<<4, 256, 0, stream>>>(gy, sums, sums + 128, NG, 128);
  k_bn_final<<<1, 128, 0, stream>>>(sums, sums + 128, gf_g, gf_b, sums + 256, sums + 384, (float)NG);
  k_gemm<128, 128, 128, true, false, true, false, 0><<<(NG + 63) / 64, 256, 0, stream>>>(
      gy, nullptr, gfW2, gfb2, sums + 256, sums + 384,
      out + (size_t)NN * 64 + (size_t)NE * 16, NG, nullptr, nullptr, nullptr);

  // ---- edge_attr passthrough ----
  int n4 = NE * 16 / 4;
  k_copy4<<<(n4 + 255) / 256, 256, 0, stream>>>((const float4*)edge_attr,
                                                (float4*)(out + (size_t)NN * 64), n4);
}

// Round 8
// 747.225 us; speedup vs baseline: 2.3260x; 2.3260x over previous
//
#include <hip/hip_runtime.h>

#define NN 50000
#define NE 1600000
#define NG 512
#define HD 128
#define NGRP 8
#define GRPSZ ((NN + NGRP - 1) / NGRP)   // 6250
#define PCAP 28672                        // per (group,sub) pair capacity (exp ~25K)

typedef __attribute__((ext_vector_type(8))) short bf16x8;
typedef __attribute__((ext_vector_type(4))) float f32x4;

static __device__ __forceinline__ unsigned bf16rn(float x) {
  unsigned b = __float_as_uint(x);
  return (b + 0x7FFFu + ((b >> 16) & 1u)) >> 16;
}
static __device__ __forceinline__ float bf16tof(unsigned short u) {
  return __uint_as_float(((unsigned)u) << 16);
}

// ---------------- edge partition: LDS-staged, coarse-grained global atomics ----------------
// Each block stages edges into 8 LDS buckets; flushes 256-entry coalesced chunks
// with ONE global atomic per flush (vs per-wave-per-bucket before: 200K -> ~8K atomics).
__global__ void __launch_bounds__(256) k_part(const int* __restrict__ src,
                                              const int* __restrict__ dst,
                                              uint2* __restrict__ pairs,
                                              int* __restrict__ pcnt) {
  __shared__ uint2 buf[8][512];
  __shared__ int lcnt[8];
  __shared__ int gbase[8];
  __shared__ int nfl[8];
  const int tid = threadIdx.x;
  const int b = blockIdx.x & 7;
  if (tid < 8) lcnt[tid] = 0;
  __syncthreads();
  const int stride = gridDim.x * 256;
  for (int base_e = blockIdx.x * 256; base_e < NE; base_e += stride) {
    int e = base_e + tid;
    bool valid = e < NE;
    if (valid) {
      int d = dst[e];
      int s = src[e];
      int g = d / GRPSZ;
      int pos = atomicAdd(&lcnt[g], 1);      // LDS atomic: cheap
      buf[g][pos] = make_uint2((unsigned)d, (unsigned)s);
    }
    __syncthreads();
    if (tid < 8) {
      int c = lcnt[tid];
      int nf = (c >= 256) ? 256 : 0;
      nfl[tid] = nf;
      gbase[tid] = nf ? atomicAdd(&pcnt[tid * 8 + b], nf) : 0;
    }
    __syncthreads();
#pragma unroll
    for (int g0 = 0; g0 < 8; ++g0) {
      if (nfl[g0]) {
        int gb = gbase[g0] + tid;
        if (gb < PCAP)
          pairs[(size_t)(g0 * 8 + b) * PCAP + gb] = buf[g0][tid];
      }
    }
    __syncthreads();
#pragma unroll
    for (int g0 = 0; g0 < 8; ++g0) {
      if (nfl[g0]) {
        int rem = lcnt[g0] - 256;            // < 256: no overlap with [256, 256+rem)
        if (tid < rem) buf[g0][tid] = buf[g0][256 + tid];
      }
    }
    __syncthreads();
    if (tid < 8 && nfl[tid]) lcnt[tid] -= 256;
    __syncthreads();
  }
  // epilogue flush
  if (tid < 8) {
    int c = lcnt[tid];
    gbase[tid] = c ? atomicAdd(&pcnt[tid * 8 + b], c) : 0;
  }
  __syncthreads();
#pragma unroll
  for (int g0 = 0; g0 < 8; ++g0) {
    int c = lcnt[g0];
    if (tid < c) {
      int gb = gbase[g0] + tid;
      if (gb < PCAP)
        pairs[(size_t)(g0 * 8 + b) * PCAP + gb] = buf[g0][tid];
    }
  }
}

// ---------------- degree count from grouped pairs (XCD-local atomics) ----------------
__global__ void k_deg2(const uint2* __restrict__ pairs, const int* __restrict__ pcnt,
                       int* __restrict__ deg) {
  int g = blockIdx.x & 7;
  int bi = blockIdx.x >> 3;
  int nb = gridDim.x >> 3;
  for (int sub = 0; sub < 8; ++sub) {
    int cnt = min(pcnt[g * 8 + sub], PCAP);
    const uint2* lst = pairs + (size_t)(g * 8 + sub) * PCAP;
    for (int i = bi * 256 + (int)threadIdx.x; i < cnt; i += nb * 256)
      atomicAdd(&deg[lst[i].x], 1);
  }
}

// ---------------- scatter from grouped pairs ----------------
__global__ void k_scat2(const uint2* __restrict__ pairs, const int* __restrict__ pcnt,
                        int* __restrict__ cursor, int* __restrict__ csr_src) {
  int g = blockIdx.x & 7;
  int bi = blockIdx.x >> 3;
  int nb = gridDim.x >> 3;
  for (int sub = 0; sub < 8; ++sub) {
    int cnt = min(pcnt[g * 8 + sub], PCAP);
    const uint2* lst = pairs + (size_t)(g * 8 + sub) * PCAP;
    for (int i = bi * 256 + (int)threadIdx.x; i < cnt; i += nb * 256) {
      uint2 p = lst[i];
      int pos = atomicAdd(&cursor[p.x], 1);
      csr_src[pos] = (int)p.y;
    }
  }
}

__global__ void k_scan_block(const int* __restrict__ in, int* __restrict__ out,
                             int* __restrict__ bsum, int n) {
  __shared__ int tmp[1024];
  int i = blockIdx.x * 1024 + threadIdx.x;
  int v = (i < n) ? in[i] : 0;
  tmp[threadIdx.x] = v;
  __syncthreads();
  for (int off = 1; off < 1024; off <<= 1) {
    int t = (threadIdx.x >= (unsigned)off) ? tmp[threadIdx.x - off] : 0;
    __syncthreads();
    tmp[threadIdx.x] += t;
    __syncthreads();
  }
  if (i < n) out[i] = tmp[threadIdx.x] - v;   // exclusive
  if (threadIdx.x == 1023 && bsum) bsum[blockIdx.x] = tmp[1023];
}

__global__ void k_scan_small(int* __restrict__ a, int n) {
  __shared__ int tmp[1024];
  int v = ((int)threadIdx.x < n) ? a[threadIdx.x] : 0;
  tmp[threadIdx.x] = v;
  __syncthreads();
  for (int off = 1; off < 1024; off <<= 1) {
    int t = (threadIdx.x >= (unsigned)off) ? tmp[threadIdx.x - off] : 0;
    __syncthreads();
    tmp[threadIdx.x] += t;
    __syncthreads();
  }
  if ((int)threadIdx.x < n) a[threadIdx.x] = tmp[threadIdx.x] - v;
}

__global__ void k_scan_add(int* __restrict__ out, const int* __restrict__ bsum, int n) {
  int i = blockIdx.x * 1024 + threadIdx.x;
  if (i < n) out[i] += bsum[blockIdx.x];
  if (blockIdx.x == 0 && threadIdx.x == 0) out[n] = NE;  // row_ptr[N] = E
}

__global__ void k_copy_int(const int* __restrict__ a, int* __restrict__ b, int n) {
  int i = blockIdx.x * 256 + threadIdx.x;
  if (i < n) b[i] = a[i];
}

// ---------------- graph segment bounds (batch is sorted) ----------------
__global__ void k_init_bounds(int* __restrict__ gs, int* __restrict__ ge) {
  int g = blockIdx.x * 256 + threadIdx.x;
  if (g < NG) { gs[g] = NN; ge[g] = 0; }
}
__global__ void k_bounds(const int* __restrict__ batch, int* __restrict__ gs, int* __restrict__ ge) {
  int n = blockIdx.x * 256 + threadIdx.x;
  if (n < NN) {
    int b = batch[n];
    atomicMin(&gs[b], n);
    atomicMax(&ge[b], n + 1);
  }
}

// ---------------- fp32 -> bf16 convert ----------------
__global__ void k_cvt(const float* __restrict__ a, unsigned short* __restrict__ b, int n) {
  int i = blockIdx.x * 256 + threadIdx.x;
  if (i < n) b[i] = (unsigned short)bf16rn(a[i]);
}

// ---------------- GAT softmax + aggregate (bf16 in, bf16 out) ----------------
__global__ void k_gat_agg(const unsigned* __restrict__ nf16, const float* __restrict__ e1,
                          const int* __restrict__ row_ptr, const int* __restrict__ csr_src,
                          unsigned short* __restrict__ agg16) {
  int node = blockIdx.x * 4 + (threadIdx.x >> 6);
  int lane = threadIdx.x & 63;
  if (node >= NN) return;
  int s = row_ptr[node], e = row_ptr[node + 1];
  const int q = lane >> 4;
  const int c = lane & 15;

  float acc[8];
#pragma unroll
  for (int i = 0; i < 8; ++i) acc[i] = 0.f;
  float zloc = 0.f;

  int jj = s + q;
  bool v0 = jj < e;
  int sc = v0 ? csr_src[jj] : 0;
  float w = v0 ? e1[sc] : 0.f;
  uint4 u = *(const uint4*)(nf16 + (size_t)sc * 64 + c * 4);

  for (int j = s; j < e; j += 4) {
    int jn = j + 4 + q;
    bool vn = jn < e;
    int scn = vn ? csr_src[jn] : 0;
    float wn = vn ? e1[scn] : 0.f;
    uint4 un = *(const uint4*)(nf16 + (size_t)scn * 64 + c * 4);
    zloc += w;
    acc[0] = fmaf(w, __uint_as_float(u.x << 16), acc[0]);
    acc[1] = fmaf(w, __uint_as_float(u.x & 0xFFFF0000u), acc[1]);
    acc[2] = fmaf(w, __uint_as_float(u.y << 16), acc[2]);
    acc[3] = fmaf(w, __uint_as_float(u.y & 0xFFFF0000u), acc[3]);
    acc[4] = fmaf(w, __uint_as_float(u.z << 16), acc[4]);
    acc[5] = fmaf(w, __uint_as_float(u.z & 0xFFFF0000u), acc[5]);
    acc[6] = fmaf(w, __uint_as_float(u.w << 16), acc[6]);
    acc[7] = fmaf(w, __uint_as_float(u.w & 0xFFFF0000u), acc[7]);
    sc = scn; w = wn; u = un;
  }

  zloc += __shfl_xor(zloc, 16);
  zloc += __shfl_xor(zloc, 32);
  float inv = (zloc > 0.f) ? 1.f / zloc : 0.f;
#pragma unroll
  for (int i = 0; i < 8; ++i) {
    acc[i] += __shfl_xor(acc[i], 16);
    acc[i] += __shfl_xor(acc[i], 32);
    acc[i] *= inv;
  }
  if (q == 0) {
    uint4 pk;
    pk.x = bf16rn(acc[0]) | (bf16rn(acc[1]) << 16);
    pk.y = bf16rn(acc[2]) | (bf16rn(acc[3]) << 16);
    pk.z = bf16rn(acc[4]) | (bf16rn(acc[5]) << 16);
    pk.w = bf16rn(acc[6]) | (bf16rn(acc[7]) << 16);
    *(uint4*)(agg16 + (size_t)node * HD + c * 8) = pk;
  }
}

// ---------------- MFMA bf16 GEMM (direct-from-global fragments) ----------------
template <int K, int KA, int HO, bool RELUOUT, bool BIAS, bool OUTF32, bool OUT16, int DOTM>
__global__ void __launch_bounds__(256) k_mfma(
    const unsigned short* __restrict__ A1, const unsigned short* __restrict__ A2,
    const unsigned short* __restrict__ W16, const float* __restrict__ bias,
    float* __restrict__ outf, unsigned short* __restrict__ out16,
    const float* __restrict__ dvec, float* __restrict__ dout, int nrows) {
  constexpr int NT = HO / 16;
  const int l = threadIdx.x & 63;
  const int w = threadIdx.x >> 6;
  const int lr = l & 15;
  const int q = l >> 4;
  const int row0 = blockIdx.x * 64 + w * 16;
  const int arow = min(row0 + lr, nrows - 1);
  const unsigned short* pa1 = A1 + (size_t)arow * KA;
  const unsigned short* pa2 = (KA < K) ? (A2 + (size_t)arow * (K - KA)) : nullptr;

  f32x4 acc[NT];
#pragma unroll
  for (int t = 0; t < NT; ++t) acc[t] = (f32x4){0.f, 0.f, 0.f, 0.f};

#pragma unroll
  for (int s = 0; s < K / 32; ++s) {
    const int kg = s * 32 + q * 8;
    bf16x8 af;
    if constexpr (KA == K) {
      af = *(const bf16x8*)(pa1 + kg);
    } else {
      af = (s * 32 < KA) ? *(const bf16x8*)(pa1 + kg)
                         : *(const bf16x8*)(pa2 + (kg - KA));
    }
#pragma unroll
    for (int t = 0; t < NT; ++t) {
      bf16x8 bfr = *(const bf16x8*)(W16 + (size_t)(t * 16 + lr) * K + kg);
      acc[t] = __builtin_amdgcn_mfma_f32_16x16x32_bf16(af, bfr, acc[t], 0, 0, 0);
    }
  }

  float bv[BIAS ? NT : 1];
  if constexpr (BIAS) {
#pragma unroll
    for (int t = 0; t < NT; ++t) bv[t] = bias[t * 16 + lr];
  }
  float dv[DOTM == 1 ? NT : 1];
  if constexpr (DOTM == 1) {
#pragma unroll
    for (int t = 0; t < NT; ++t) dv[t] = dvec[t * 16 + lr];
  }
  float p[4] = {0.f, 0.f, 0.f, 0.f};
#pragma unroll
  for (int j = 0; j < 4; ++j) {
    int n = row0 + q * 4 + j;
    bool ok = n < nrows;
#pragma unroll
    for (int t = 0; t < NT; ++t) {
      float v = acc[t][j];
      if constexpr (BIAS) v += bv[t];
      if constexpr (RELUOUT) v = fmaxf(v, 0.f);
      if (ok) {
        if constexpr (OUTF32) outf[(size_t)n * HO + t * 16 + lr] = v;
        if constexpr (OUT16) out16[(size_t)n * HO + t * 16 + lr] = (unsigned short)bf16rn(v);
      }
      if constexpr (DOTM == 1) p[j] = fmaf(v, dv[t], p[j]);
      if constexpr (DOTM == 2) p[j] = fmaf(v, v, p[j]);
    }
  }
  if constexpr (DOTM != 0) {
#pragma unroll
    for (int j = 0; j < 4; ++j) {
      p[j] += __shfl_xor(p[j], 1);
      p[j] += __shfl_xor(p[j], 2);
      p[j] += __shfl_xor(p[j], 4);
      p[j] += __shfl_xor(p[j], 8);
    }
    if (lr == 0) {
#pragma unroll
      for (int j = 0; j < 4; ++j) {
        int n = row0 + q * 4 + j;
        if (n < nrows) dout[n] = (DOTM == 1) ? __expf(p[j]) : p[j];
      }
    }
  }
}

// ---------------- fp32 register-tiled GEMM (input + gf head) ----------------
template <int K, int KA, int HO, bool PRE, bool RELUOUT, bool BIAS, bool OUT16, int DOTM>
__global__ void __launch_bounds__(256) k_gemm(
    const float* __restrict__ inA, const float* __restrict__ inB,
    const float* __restrict__ W, const float* __restrict__ bias,
    const float* __restrict__ preA, const float* __restrict__ preB,
    float* __restrict__ out, int nrows,
    unsigned* __restrict__ out16, const float* __restrict__ dvec,
    float* __restrict__ dout) {
  constexpr int KC = 64;
  constexpr int BM = 64;
  constexpr int MT = 4;
  constexpr int NT = HO / 16;
  constexpr int LDW = HO + 4;
  constexpr int LDA = KC + 4;

  __shared__ float Wl[KC * LDW];
  __shared__ float inl[BM * LDA];

  const int tid = threadIdx.x;
  const int tr = tid >> 4;
  const int tc = tid & 15;
  const int row0 = blockIdx.x * BM;
  const int r0 = tr * MT;
  const int c0 = tc * NT;

  float acc[MT][NT];
#pragma unroll
  for (int i = 0; i < MT; ++i)
#pragma unroll
    for (int j = 0; j < NT; ++j) acc[i][j] = BIAS ? bias[c0 + j] : 0.f;

  for (int cc = 0; cc < K / KC; ++cc) {
    const int k0 = cc * KC;
    if (cc) __syncthreads();
    for (int idx = tid; idx < HO * (KC / 4); idx += 256) {
      int h = idx >> 4;
      int qq = idx & 15;
      float4 w = *(const float4*)(W + (size_t)h * K + k0 + qq * 4);
      Wl[(qq * 4 + 0) * LDW + h] = w.x;
      Wl[(qq * 4 + 1) * LDW + h] = w.y;
      Wl[(qq * 4 + 2) * LDW + h] = w.z;
      Wl[(qq * 4 + 3) * LDW + h] = w.w;
    }
    for (int idx = tid; idx < BM * (KC / 4); idx += 256) {
      int r = idx >> 4;
      int qq = idx & 15;
      int n = row0 + r;
      int kg = k0 + qq * 4;
      float4 v = make_float4(0.f, 0.f, 0.f, 0.f);
      if (n < nrows) {
        if constexpr (KA == K) {
          v = *(const float4*)(inA + (size_t)n * K + kg);
        } else {
          if (k0 < KA) v = *(const float4*)(inA + (size_t)n * KA + kg);
          else         v = *(const float4*)(inB + (size_t)n * (K - KA) + kg - KA);
        }
      }
      if constexpr (PRE) {
        v.x = fmaxf(v.x * preA[kg + 0] + preB[kg + 0], 0.f);
        v.y = fmaxf(v.y * preA[kg + 1] + preB[kg + 1], 0.f);
        v.z = fmaxf(v.z * preA[kg + 2] + preB[kg + 2], 0.f);
        v.w = fmaxf(v.w * preA[kg + 3] + preB[kg + 3], 0.f);
      }
      *(float4*)(inl + r * LDA + qq * 4) = v;
    }
    __syncthreads();
#pragma unroll 8
    for (int k = 0; k < KC; ++k) {
      float a[MT];
#pragma unroll
      for (int i = 0; i < MT; ++i) a[i] = inl[(r0 + i) * LDA + k];
      float4 b0 = *(const float4*)(Wl + k * LDW + c0);
#pragma unroll
      for (int i = 0; i < MT; ++i) {
        acc[i][0] = fmaf(a[i], b0.x, acc[i][0]);
        acc[i][1] = fmaf(a[i], b0.y, acc[i][1]);
        acc[i][2] = fmaf(a[i], b0.z, acc[i][2]);
        acc[i][3] = fmaf(a[i], b0.w, acc[i][3]);
      }
      if constexpr (NT == 8) {
        float4 b1 = *(const float4*)(Wl + k * LDW + c0 + 4);
#pragma unroll
        for (int i = 0; i < MT; ++i) {
          acc[i][4] = fmaf(a[i], b1.x, acc[i][4]);
          acc[i][5] = fmaf(a[i], b1.y, acc[i][5]);
          acc[i][6] = fmaf(a[i], b1.z, acc[i][6]);
          acc[i][7] = fmaf(a[i], b1.w, acc[i][7]);
        }
      }
    }
  }
  float dv[DOTM == 1 ? NT : 1];
  if constexpr (DOTM == 1) {
#pragma unroll
    for (int j = 0; j < NT; ++j) dv[j] = dvec[c0 + j];
  }
#pragma unroll
  for (int i = 0; i < MT; ++i) {
    int n = row0 + r0 + i;
    if constexpr (RELUOUT) {
#pragma unroll
      for (int j = 0; j < NT; ++j) acc[i][j] = fmaxf(acc[i][j], 0.f);
    }
    if (n < nrows) {
      float4 o0 = make_float4(acc[i][0], acc[i][1], acc[i][2], acc[i][3]);
      *(float4*)(out + (size_t)n * HO + c0) = o0;
      if constexpr (NT == 8) {
        float4 o1 = make_float4(acc[i][4], acc[i][5], acc[i][6], acc[i][7]);
        *(float4*)(out + (size_t)n * HO + c0 + 4) = o1;
      }
      if constexpr (OUT16 && NT == 8) {
        uint4 pk;
        pk.x = bf16rn(acc[i][0]) | (bf16rn(acc[i][1]) << 16);
        pk.y = bf16rn(acc[i][2]) | (bf16rn(acc[i][3]) << 16);
        pk.z = bf16rn(acc[i][4]) | (bf16rn(acc[i][5]) << 16);
        pk.w = bf16rn(acc[i][6]) | (bf16rn(acc[i][7]) << 16);
        *(uint4*)(out16 + (size_t)n * 64 + tc * 4) = pk;
      }
    }
    if constexpr (DOTM != 0) {
      float p = 0.f;
#pragma unroll
      for (int j = 0; j < NT; ++j)
        p = fmaf(acc[i][j], (DOTM == 1) ? dv[j] : acc[i][j], p);
      p += __shfl_xor(p, 1);
      p += __shfl_xor(p, 2);
      p += __shfl_xor(p, 4);
      p += __shfl_xor(p, 8);
      if (tc == 0 && n < nrows) dout[n] = (DOTM == 1) ? __expf(p) : p;
    }
  }
}

// ---------------- attention pooling (block per graph; nf in bf16) ----------------
__global__ void k_pool(const unsigned short* __restrict__ nf16, const float* __restrict__ r,
                       const int* __restrict__ gs, const int* __restrict__ ge,
                       float* __restrict__ alpha, float* __restrict__ gf) {
  int g = blockIdx.x;
  int s = gs[g], e = ge[g];
  __shared__ float red[256];
  for (int it = 0; it < 3; ++it) {
    float lm = -INFINITY;
    for (int n = s + threadIdx.x; n < e; n += 256) {
      float l = r[n];
      if (it) l *= alpha[n];
      lm = fmaxf(lm, l);
    }
    red[threadIdx.x] = lm;
    __syncthreads();
    for (int off = 128; off > 0; off >>= 1) {
      if ((int)threadIdx.x < off) red[threadIdx.x] = fmaxf(red[threadIdx.x], red[threadIdx.x + off]);
      __syncthreads();
    }
    float m = red[0];
    __syncthreads();
    float zz = 0.f;
    for (int n = s + threadIdx.x; n < e; n += 256) {
      float l = r[n];
      if (it) l *= alpha[n];
      zz += __expf(l - m);
    }
    red[threadIdx.x] = zz;
    __syncthreads();
    for (int off = 128; off > 0; off >>= 1) {
      if ((int)threadIdx.x < off) red[threadIdx.x] += red[threadIdx.x + off];
      __syncthreads();
    }
    float z = red[0];
    __syncthreads();
    float invz = 1.f / z;
    for (int n = s + threadIdx.x; n < e; n += 256) {
      float l = r[n];
      if (it) l *= alpha[n];
      alpha[n] = __expf(l - m) * invz;
    }
    __syncthreads();
  }
  int c = threadIdx.x & 127;
  int rr2 = threadIdx.x >> 7;
  float acc = 0.f;
  for (int n = s + rr2; n < e; n += 2)
    acc += alpha[n] * bf16tof(nf16[(size_t)n * HD + c]);
  red[threadIdx.x] = acc;
  __syncthreads();
  if (rr2 == 0) gf[(size_t)g * HD + c] = red[threadIdx.x] + red[threadIdx.x + 128];
}

// ---------------- BN stats / apply ----------------
__global__ void k_colstats(const float* __restrict__ y, float* __restrict__ sum,
                           float* __restrict__ sumsq, int R, int CH) {
  int c = threadIdx.x & 127;
  int rr = threadIdx.x >> 7;
  int r0 = blockIdx.x * CH;
  int r1 = min(R, r0 + CH);
  float s = 0.f, q = 0.f;
  for (int r = r0 + rr; r < r1; r += 2) {
    float v = y[(size_t)r * HD + c];
    s += v;
    q += v * v;
  }
  __shared__ float ls[256], lq[256];
  ls[threadIdx.x] = s;
  lq[threadIdx.x] = q;
  __syncthreads();
  if (rr == 0) {
    s += ls[threadIdx.x + 128];
    q += lq[threadIdx.x + 128];
    atomicAdd(&sum[c], s);
    atomicAdd(&sumsq[c], q);
  }
}

__global__ void k_bn_final(const float* __restrict__ sum, const float* __restrict__ sumsq,
                           const float* __restrict__ g, const float* __restrict__ b,
                           float* __restrict__ A, float* __restrict__ B, float R) {
  int c = threadIdx.x;
  float mu = sum[c] / R;
  float var = sumsq[c] / R - mu * mu;
  float a = g[c] * rsqrtf(var + 1e-5f);
  A[c] = a;
  B[c] = b[c] - mu * a;
}

// z16 = bf16(relu(A*y+B)) elementwise over [NN][128]
__global__ void k_bnapply(const float* __restrict__ y, const float* __restrict__ Ac,
                          const float* __restrict__ Bc, unsigned short* __restrict__ z) {
  int i = blockIdx.x * 256 + threadIdx.x;
  if (i >= NN * 16) return;
  int c = (i & 15) * 8;
  const float4* yp = (const float4*)y + (size_t)i * 2;
  float4 v0 = yp[0], v1 = yp[1];
  float4 a0 = *(const float4*)(Ac + c), a1 = *(const float4*)(Ac + c + 4);
  float4 b0 = *(const float4*)(Bc + c), b1 = *(const float4*)(Bc + c + 4);
  float r0 = fmaxf(fmaf(v0.x, a0.x, b0.x), 0.f);
  float r1 = fmaxf(fmaf(v0.y, a0.y, b0.y), 0.f);
  float r2 = fmaxf(fmaf(v0.z, a0.z, b0.z), 0.f);
  float r3 = fmaxf(fmaf(v0.w, a0.w, b0.w), 0.f);
  float r4 = fmaxf(fmaf(v1.x, a1.x, b1.x), 0.f);
  float r5 = fmaxf(fmaf(v1.y, a1.y, b1.y), 0.f);
  float r6 = fmaxf(fmaf(v1.z, a1.z, b1.z), 0.f);
  float r7 = fmaxf(fmaf(v1.w, a1.w, b1.w), 0.f);
  uint4 pk;
  pk.x = bf16rn(r0) | (bf16rn(r1) << 16);
  pk.y = bf16rn(r2) | (bf16rn(r3) << 16);
  pk.z = bf16rn(r4) | (bf16rn(r5) << 16);
  pk.w = bf16rn(r6) | (bf16rn(r7) << 16);
  *(uint4*)(z + (size_t)i * 8) = pk;
}

__global__ void k_copy4(const float4* __restrict__ a, float4* __restrict__ b, int n) {
  int i = blockIdx.x * 256 + threadIdx.x;
  if (i < n) b[i] = a[i];
}

extern "C" void kernel_launch(void* const* d_in, const int* in_sizes, int n_in,
                              void* d_out, int out_size, void* d_ws, size_t ws_size,
                              hipStream_t stream) {
  const float* x        = (const float*)d_in[0];
  const int*   ei       = (const int*)d_in[1];
  const float* edge_attr= (const float*)d_in[2];
  const int*   batch    = (const int*)d_in[3];
  const float* Wi       = (const float*)d_in[5];
  const float* bi       = (const float*)d_in[6];
  const float* gat_W    = (const float*)d_in[7];
  const float* gat_a    = (const float*)d_in[8];
  const float* nfW1     = (const float*)d_in[9];
  const float* nfb1     = (const float*)d_in[10];
  const float* nf_g     = (const float*)d_in[11];
  const float* nf_b     = (const float*)d_in[12];
  const float* nfW2     = (const float*)d_in[13];
  const float* nfb2     = (const float*)d_in[14];
  const float* gfW1     = (const float*)d_in[15];
  const float* gfb1     = (const float*)d_in[16];
  const float* gf_g     = (const float*)d_in[17];
  const float* gf_b     = (const float*)d_in[18];
  const float* gfW2     = (const float*)d_in[19];
  const float* gfb2     = (const float*)d_in[20];

  float* out = (float*)d_out;

  unsigned short* nf16A = (unsigned short*)d_ws;          // NN*128
  unsigned short* nf16B = nf16A + (size_t)NN * HD;
  unsigned short* agg16 = nf16B + (size_t)NN * HD;
  unsigned short* z16   = agg16 + (size_t)NN * HD;
  unsigned short* wt_gat = z16 + (size_t)NN * HD;          // 3*128*256
  unsigned short* wt_nf1 = wt_gat + 3 * 128 * 256;         // 128*128
  unsigned short* wt_nf2 = wt_nf1 + 128 * 128;             // 64*128
  float* nfA   = (float*)(wt_nf2 + 64 * 128);              // [NN][128] (y scratch)
  float* e1v   = nfA + (size_t)NN * HD;
  float* rv    = e1v + NN;
  float* alpha = rv + NN;
  float* gf    = alpha + NN;
  float* gy    = gf + (size_t)NG * HD;
  float* sums  = gy + (size_t)NG * HD;   // 512: sum,sumsq,A,B
  int* deg     = (int*)(sums + 512);
  int* row_ptr = deg + NN;
  int* cursor  = row_ptr + NN + 1;
  int* csr_src = cursor + NN;
  int* bsum    = csr_src + NE;
  int* gs      = bsum + 64;
  int* ge      = gs + NG;
  int* pcnt    = ge + NG;                // 64 counters
  // pair lists alias nfA scratch (used strictly before nfA is written)
  uint2* pairs = (uint2*)nfA;            // 64 * PCAP * 8B = 14.7MB < 25.6MB

  const int* src  = ei;
  const int* dstp = ei + NE;

  // ---- CSR by dst: LDS-staged partition, then XCD-local count & scatter ----
  hipMemsetAsync(deg, 0, NN * sizeof(int), stream);
  hipMemsetAsync(pcnt, 0, 64 * sizeof(int), stream);
  k_part<<<512, 256, 0, stream>>>(src, dstp, pairs, pcnt);
  k_deg2<<<2048, 256, 0, stream>>>(pairs, pcnt, deg);
  int nsb = (NN + 1023) / 1024;
  k_scan_block<<<nsb, 1024, 0, stream>>>(deg, row_ptr, bsum, NN);
  k_scan_small<<<1, 1024, 0, stream>>>(bsum, nsb);
  k_scan_add<<<nsb, 1024, 0, stream>>>(row_ptr, bsum, NN);
  k_copy_int<<<(NN + 255) / 256, 256, 0, stream>>>(row_ptr, cursor, NN);
  k_scat2<<<2048, 256, 0, stream>>>(pairs, pcnt, cursor, csr_src);

  // ---- graph bounds ----
  k_init_bounds<<<2, 256, 0, stream>>>(gs, ge);
  k_bounds<<<(NN + 255) / 256, 256, 0, stream>>>(batch, gs, ge);

  // ---- weights -> bf16 ----
  k_cvt<<<(3 * 128 * 256 + 255) / 256, 256, 0, stream>>>(gat_W, wt_gat, 3 * 128 * 256);
  k_cvt<<<(128 * 128 + 255) / 256, 256, 0, stream>>>(nfW1, wt_nf1, 128 * 128);
  k_cvt<<<(64 * 128 + 255) / 256, 256, 0, stream>>>(nfW2, wt_nf2, 64 * 128);

  // ---- input linear (fp32): nf16A + e1 = exp(nf . a0) ----
  k_gemm<64, 64, 128, false, false, true, true, 1><<<(NN + 63) / 64, 256, 0, stream>>>(
      x, nullptr, Wi, bi, nullptr, nullptr, nfA, NN, (unsigned*)nf16A, gat_a, e1v);

  // ---- 3 GAT layers (MFMA) ----
  unsigned short* cur = nf16A;
  unsigned short* nxt = nf16B;
  const int gemm_grid = (NN + 63) / 64;
  for (int l = 0; l < 3; ++l) {
    k_gat_agg<<<(NN + 3) / 4, 256, 0, stream>>>((const unsigned*)cur, e1v, row_ptr, csr_src, agg16);
    if (l < 2) {
      k_mfma<256, 128, 128, true, false, false, true, 1><<<gemm_grid, 256, 0, stream>>>(
          cur, agg16, wt_gat + (size_t)l * 128 * 256, nullptr,
          nullptr, nxt, gat_a + (size_t)(l + 1) * 256, e1v, NN);
    } else {
      k_mfma<256, 128, 128, true, false, false, true, 2><<<gemm_grid, 256, 0, stream>>>(
          cur, agg16, wt_gat + (size_t)l * 128 * 256, nullptr,
          nullptr, nxt, nullptr, rv, NN);
    }
    unsigned short* t = cur; cur = nxt; nxt = t;
  }

  // ---- attention pooling ----
  k_pool<<<NG, 256, 0, stream>>>(cur, rv, gs, ge, alpha, gf);

  // ---- nf head ----
  k_mfma<128, 128, 128, false, true, true, false, 0><<<gemm_grid, 256, 0, stream>>>(
      cur, nullptr, wt_nf1, nfb1, nfA, nullptr, nullptr, nullptr, NN);
  hipMemsetAsync(sums, 0, 256 * sizeof(float), stream);
  k_colstats<<<200, 256, 0, stream>>>(nfA, sums, sums + 128, NN, 250);
  k_bn_final<<<1, 128, 0, stream>>>(sums, sums + 128, nf_g, nf_b, sums + 256, sums + 384, (float)NN);
  k_bnapply<<<(NN * 16 + 255) / 256, 256, 0, stream>>>(nfA, sums + 256, sums + 384, z16);
  k_mfma<128, 128, 64, false, true, true, false, 0><<<gemm_grid, 256, 0, stream>>>(
      z16, nullptr, wt_nf2, nfb2, out, nullptr, nullptr, nullptr, NN);

  // ---- gf head (fp32, tiny) ----
  k_gemm<128, 128, 128, false, false, true, false, 0><<<(NG + 63) / 64, 256, 0, stream>>>(
      gf, nullptr, gfW1, gfb1, nullptr, nullptr, gy, NG, nullptr, nullptr, nullptr);
  hipMemsetAsync(sums, 0, 256 * sizeof(float), stream);
  k_colstats<<<4, 256, 0, stream>>>(gy, sums, sums + 128, NG, 128);
  k_bn_final<<<1, 128, 0, stream>>>(sums, sums + 128, gf_g, gf_b, sums + 256, sums + 384, (float)NG);
  k_gemm<128, 128, 128, true, false, true, false, 0><<<(NG + 63) / 64, 256, 0, stream>>>(
      gy, nullptr, gfW2, gfb2, sums + 256, sums + 384,
      out + (size_t)NN * 64 + (size_t)NE * 16, NG, nullptr, nullptr, nullptr);

  // ---- edge_attr passthrough ----
  int n4 = NE * 16 / 4;
  k_copy4<<<(n4 + 255) / 256, 256, 0, stream>>>((const float4*)edge_attr,
                                                (float4*)(out + (size_t)NN * 64), n4);
}

// Round 9
// 674.035 us; speedup vs baseline: 2.5786x; 1.1086x over previous
//
#include <hip/hip_runtime.h>

#define NN 50000
#define NE 1600000
#define NG 512
#define HD 128
#define NGRP 8
#define GRPSZ ((NN + NGRP - 1) / NGRP)   // 6250 (NN == 8*6250 exactly)
#define PCAP 28672                        // per (group,sub) pair capacity (exp ~25K)

typedef __attribute__((ext_vector_type(8))) short bf16x8;
typedef __attribute__((ext_vector_type(4))) float f32x4;

static __device__ __forceinline__ unsigned bf16rn(float x) {
  unsigned b = __float_as_uint(x);
  return (b + 0x7FFFu + ((b >> 16) & 1u)) >> 16;
}
static __device__ __forceinline__ float bf16tof(unsigned short u) {
  return __uint_as_float(((unsigned)u) << 16);
}

// ---------------- edge partition: LDS-staged, coarse-grained global atomics ----------------
__global__ void __launch_bounds__(256) k_part(const int* __restrict__ src,
                                              const int* __restrict__ dst,
                                              uint2* __restrict__ pairs,
                                              int* __restrict__ pcnt) {
  __shared__ uint2 buf[8][512];
  __shared__ int lcnt[8];
  __shared__ int gbase[8];
  __shared__ int nfl[8];
  const int tid = threadIdx.x;
  const int b = blockIdx.x & 7;
  if (tid < 8) lcnt[tid] = 0;
  __syncthreads();
  const int stride = gridDim.x * 256;
  for (int base_e = blockIdx.x * 256; base_e < NE; base_e += stride) {
    int e = base_e + tid;
    bool valid = e < NE;
    if (valid) {
      int d = dst[e];
      int s = src[e];
      int g = d / GRPSZ;
      int pos = atomicAdd(&lcnt[g], 1);      // LDS atomic: cheap
      buf[g][pos] = make_uint2((unsigned)d, (unsigned)s);
    }
    __syncthreads();
    if (tid < 8) {
      int c = lcnt[tid];
      int nf = (c >= 256) ? 256 : 0;
      nfl[tid] = nf;
      gbase[tid] = nf ? atomicAdd(&pcnt[tid * 8 + b], nf) : 0;
    }
    __syncthreads();
#pragma unroll
    for (int g0 = 0; g0 < 8; ++g0) {
      if (nfl[g0]) {
        int gb = gbase[g0] + tid;
        if (gb < PCAP)
          pairs[(size_t)(g0 * 8 + b) * PCAP + gb] = buf[g0][tid];
      }
    }
    __syncthreads();
#pragma unroll
    for (int g0 = 0; g0 < 8; ++g0) {
      if (nfl[g0]) {
        int rem = lcnt[g0] - 256;            // < 256: no overlap with [256, 256+rem)
        if (tid < rem) buf[g0][tid] = buf[g0][256 + tid];
      }
    }
    __syncthreads();
    if (tid < 8 && nfl[tid]) lcnt[tid] -= 256;
    __syncthreads();
  }
  // epilogue flush
  if (tid < 8) {
    int c = lcnt[tid];
    gbase[tid] = c ? atomicAdd(&pcnt[tid * 8 + b], c) : 0;
  }
  __syncthreads();
#pragma unroll
  for (int g0 = 0; g0 < 8; ++g0) {
    int c = lcnt[g0];
    if (tid < c) {
      int gb = gbase[g0] + tid;
      if (gb < PCAP)
        pairs[(size_t)(g0 * 8 + b) * PCAP + gb] = buf[g0][tid];
    }
  }
}

// ---------------- per-list LDS histogram -> global hcnt (no global atomics) ----------------
__global__ void __launch_bounds__(256) k_hist(const uint2* __restrict__ pairs,
                                              const int* __restrict__ pcnt,
                                              int* __restrict__ hcnt) {
  __shared__ int hist[GRPSZ];
  const int b = blockIdx.x;           // 64 blocks; g = b&7 keeps XCD affinity
  const int g = b & 7, sub = b >> 3;
  const int li = g * 8 + sub;
  const int lo = g * GRPSZ;
  for (int i = threadIdx.x; i < GRPSZ; i += 256) hist[i] = 0;
  __syncthreads();
  int cnt = min(pcnt[li], PCAP);
  const uint2* lst = pairs + (size_t)li * PCAP;
  for (int i = threadIdx.x; i < cnt; i += 256)
    atomicAdd(&hist[(int)lst[i].x - lo], 1);
  __syncthreads();
  for (int i = threadIdx.x; i < GRPSZ; i += 256)
    hcnt[(size_t)li * GRPSZ + i] = hist[i];
}

// ---------------- deg[d] = sum over subs of hcnt (plain reads) ----------------
__global__ void k_degsum(const int* __restrict__ hcnt, int* __restrict__ deg) {
  int d = blockIdx.x * 256 + threadIdx.x;
  if (d >= NN) return;
  int g = d / GRPSZ, i = d - g * GRPSZ;
  int s = 0;
#pragma unroll
  for (int sub = 0; sub < 8; ++sub) s += hcnt[(size_t)(g * 8 + sub) * GRPSZ + i];
  deg[d] = s;
}

// ---------------- scatter with LDS cursors (zero global atomics) ----------------
__global__ void __launch_bounds__(256) k_scat3(const uint2* __restrict__ pairs,
                                               const int* __restrict__ pcnt,
                                               const int* __restrict__ hcnt,
                                               const int* __restrict__ row_ptr,
                                               int* __restrict__ csr_src) {
  __shared__ int cur[GRPSZ];
  const int b = blockIdx.x;
  const int g = b & 7, sub = b >> 3;
  const int li = g * 8 + sub;
  const int lo = g * GRPSZ;
  for (int i = threadIdx.x; i < GRPSZ; i += 256) {
    int base = row_ptr[lo + i];
    for (int s2 = 0; s2 < sub; ++s2)
      base += hcnt[(size_t)(g * 8 + s2) * GRPSZ + i];
    cur[i] = base;
  }
  __syncthreads();
  int cnt = min(pcnt[li], PCAP);
  const uint2* lst = pairs + (size_t)li * PCAP;
  for (int i = threadIdx.x; i < cnt; i += 256) {
    uint2 p = lst[i];
    int pos = atomicAdd(&cur[(int)p.x - lo], 1);   // LDS atomic
    csr_src[pos] = (int)p.y;                        // plain store
  }
}

__global__ void k_scan_block(const int* __restrict__ in, int* __restrict__ out,
                             int* __restrict__ bsum, int n) {
  __shared__ int tmp[1024];
  int i = blockIdx.x * 1024 + threadIdx.x;
  int v = (i < n) ? in[i] : 0;
  tmp[threadIdx.x] = v;
  __syncthreads();
  for (int off = 1; off < 1024; off <<= 1) {
    int t = (threadIdx.x >= (unsigned)off) ? tmp[threadIdx.x - off] : 0;
    __syncthreads();
    tmp[threadIdx.x] += t;
    __syncthreads();
  }
  if (i < n) out[i] = tmp[threadIdx.x] - v;   // exclusive
  if (threadIdx.x == 1023 && bsum) bsum[blockIdx.x] = tmp[1023];
}

__global__ void k_scan_small(int* __restrict__ a, int n) {
  __shared__ int tmp[1024];
  int v = ((int)threadIdx.x < n) ? a[threadIdx.x] : 0;
  tmp[threadIdx.x] = v;
  __syncthreads();
  for (int off = 1; off < 1024; off <<= 1) {
    int t = (threadIdx.x >= (unsigned)off) ? tmp[threadIdx.x - off] : 0;
    __syncthreads();
    tmp[threadIdx.x] += t;
    __syncthreads();
  }
  if ((int)threadIdx.x < n) a[threadIdx.x] = tmp[threadIdx.x] - v;
}

__global__ void k_scan_add(int* __restrict__ out, const int* __restrict__ bsum, int n) {
  int i = blockIdx.x * 1024 + threadIdx.x;
  if (i < n) out[i] += bsum[blockIdx.x];
  if (blockIdx.x == 0 && threadIdx.x == 0) out[n] = NE;  // row_ptr[N] = E
}

// ---------------- graph segment bounds (batch is sorted) ----------------
__global__ void k_init_bounds(int* __restrict__ gs, int* __restrict__ ge) {
  int g = blockIdx.x * 256 + threadIdx.x;
  if (g < NG) { gs[g] = NN; ge[g] = 0; }
}
__global__ void k_bounds(const int* __restrict__ batch, int* __restrict__ gs, int* __restrict__ ge) {
  int n = blockIdx.x * 256 + threadIdx.x;
  if (n < NN) {
    int b = batch[n];
    atomicMin(&gs[b], n);
    atomicMax(&ge[b], n + 1);
  }
}

// ---------------- fp32 -> bf16 convert ----------------
__global__ void k_cvt(const float* __restrict__ a, unsigned short* __restrict__ b, int n) {
  int i = blockIdx.x * 256 + threadIdx.x;
  if (i < n) b[i] = (unsigned short)bf16rn(a[i]);
}

// ---------------- GAT softmax + aggregate (bf16 in, bf16 out) ----------------
__global__ void k_gat_agg(const unsigned* __restrict__ nf16, const float* __restrict__ e1,
                          const int* __restrict__ row_ptr, const int* __restrict__ csr_src,
                          unsigned short* __restrict__ agg16) {
  int node = blockIdx.x * 4 + (threadIdx.x >> 6);
  int lane = threadIdx.x & 63;
  if (node >= NN) return;
  int s = row_ptr[node], e = row_ptr[node + 1];
  const int q = lane >> 4;
  const int c = lane & 15;

  float acc[8];
#pragma unroll
  for (int i = 0; i < 8; ++i) acc[i] = 0.f;
  float zloc = 0.f;

  int jj = s + q;
  bool v0 = jj < e;
  int sc = v0 ? csr_src[jj] : 0;
  float w = v0 ? e1[sc] : 0.f;
  uint4 u = *(const uint4*)(nf16 + (size_t)sc * 64 + c * 4);

  for (int j = s; j < e; j += 4) {
    int jn = j + 4 + q;
    bool vn = jn < e;
    int scn = vn ? csr_src[jn] : 0;
    float wn = vn ? e1[scn] : 0.f;
    uint4 un = *(const uint4*)(nf16 + (size_t)scn * 64 + c * 4);
    zloc += w;
    acc[0] = fmaf(w, __uint_as_float(u.x << 16), acc[0]);
    acc[1] = fmaf(w, __uint_as_float(u.x & 0xFFFF0000u), acc[1]);
    acc[2] = fmaf(w, __uint_as_float(u.y << 16), acc[2]);
    acc[3] = fmaf(w, __uint_as_float(u.y & 0xFFFF0000u), acc[3]);
    acc[4] = fmaf(w, __uint_as_float(u.z << 16), acc[4]);
    acc[5] = fmaf(w, __uint_as_float(u.z & 0xFFFF0000u), acc[5]);
    acc[6] = fmaf(w, __uint_as_float(u.w << 16), acc[6]);
    acc[7] = fmaf(w, __uint_as_float(u.w & 0xFFFF0000u), acc[7]);
    sc = scn; w = wn; u = un;
  }

  zloc += __shfl_xor(zloc, 16);
  zloc += __shfl_xor(zloc, 32);
  float inv = (zloc > 0.f) ? 1.f / zloc : 0.f;
#pragma unroll
  for (int i = 0; i < 8; ++i) {
    acc[i] += __shfl_xor(acc[i], 16);
    acc[i] += __shfl_xor(acc[i], 32);
    acc[i] *= inv;
  }
  if (q == 0) {
    uint4 pk;
    pk.x = bf16rn(acc[0]) | (bf16rn(acc[1]) << 16);
    pk.y = bf16rn(acc[2]) | (bf16rn(acc[3]) << 16);
    pk.z = bf16rn(acc[4]) | (bf16rn(acc[5]) << 16);
    pk.w = bf16rn(acc[6]) | (bf16rn(acc[7]) << 16);
    *(uint4*)(agg16 + (size_t)node * HD + c * 8) = pk;
  }
}

// ---------------- MFMA bf16 GEMM (direct-from-global fragments) ----------------
template <int K, int KA, int HO, bool RELUOUT, bool BIAS, bool OUTF32, bool OUT16, int DOTM>
__global__ void __launch_bounds__(256) k_mfma(
    const unsigned short* __restrict__ A1, const unsigned short* __restrict__ A2,
    const unsigned short* __restrict__ W16, const float* __restrict__ bias,
    float* __restrict__ outf, unsigned short* __restrict__ out16,
    const float* __restrict__ dvec, float* __restrict__ dout, int nrows) {
  constexpr int NT = HO / 16;
  const int l = threadIdx.x & 63;
  const int w = threadIdx.x >> 6;
  const int lr = l & 15;
  const int q = l >> 4;
  const int row0 = blockIdx.x * 64 + w * 16;
  const int arow = min(row0 + lr, nrows - 1);
  const unsigned short* pa1 = A1 + (size_t)arow * KA;
  const unsigned short* pa2 = (KA < K) ? (A2 + (size_t)arow * (K - KA)) : nullptr;

  f32x4 acc[NT];
#pragma unroll
  for (int t = 0; t < NT; ++t) acc[t] = (f32x4){0.f, 0.f, 0.f, 0.f};

#pragma unroll
  for (int s = 0; s < K / 32; ++s) {
    const int kg = s * 32 + q * 8;
    bf16x8 af;
    if constexpr (KA == K) {
      af = *(const bf16x8*)(pa1 + kg);
    } else {
      af = (s * 32 < KA) ? *(const bf16x8*)(pa1 + kg)
                         : *(const bf16x8*)(pa2 + (kg - KA));
    }
#pragma unroll
    for (int t = 0; t < NT; ++t) {
      bf16x8 bfr = *(const bf16x8*)(W16 + (size_t)(t * 16 + lr) * K + kg);
      acc[t] = __builtin_amdgcn_mfma_f32_16x16x32_bf16(af, bfr, acc[t], 0, 0, 0);
    }
  }

  float bv[BIAS ? NT : 1];
  if constexpr (BIAS) {
#pragma unroll
    for (int t = 0; t < NT; ++t) bv[t] = bias[t * 16 + lr];
  }
  float dv[DOTM == 1 ? NT : 1];
  if constexpr (DOTM == 1) {
#pragma unroll
    for (int t = 0; t < NT; ++t) dv[t] = dvec[t * 16 + lr];
  }
  float p[4] = {0.f, 0.f, 0.f, 0.f};
#pragma unroll
  for (int j = 0; j < 4; ++j) {
    int n = row0 + q * 4 + j;
    bool ok = n < nrows;
#pragma unroll
    for (int t = 0; t < NT; ++t) {
      float v = acc[t][j];
      if constexpr (BIAS) v += bv[t];
      if constexpr (RELUOUT) v = fmaxf(v, 0.f);
      if (ok) {
        if constexpr (OUTF32) outf[(size_t)n * HO + t * 16 + lr] = v;
        if constexpr (OUT16) out16[(size_t)n * HO + t * 16 + lr] = (unsigned short)bf16rn(v);
      }
      if constexpr (DOTM == 1) p[j] = fmaf(v, dv[t], p[j]);
      if constexpr (DOTM == 2) p[j] = fmaf(v, v, p[j]);
    }
  }
  if constexpr (DOTM != 0) {
#pragma unroll
    for (int j = 0; j < 4; ++j) {
      p[j] += __shfl_xor(p[j], 1);
      p[j] += __shfl_xor(p[j], 2);
      p[j] += __shfl_xor(p[j], 4);
      p[j] += __shfl_xor(p[j], 8);
    }
    if (lr == 0) {
#pragma unroll
      for (int j = 0; j < 4; ++j) {
        int n = row0 + q * 4 + j;
        if (n < nrows) dout[n] = (DOTM == 1) ? __expf(p[j]) : p[j];
      }
    }
  }
}

// ---------------- fp32 register-tiled GEMM (input + gf head) ----------------
template <int K, int KA, int HO, bool PRE, bool RELUOUT, bool BIAS, bool OUT16, int DOTM>
__global__ void __launch_bounds__(256) k_gemm(
    const float* __restrict__ inA, const float* __restrict__ inB,
    const float* __restrict__ W, const float* __restrict__ bias,
    const float* __restrict__ preA, const float* __restrict__ preB,
    float* __restrict__ out, int nrows,
    unsigned* __restrict__ out16, const float* __restrict__ dvec,
    float* __restrict__ dout) {
  constexpr int KC = 64;
  constexpr int BM = 64;
  constexpr int MT = 4;
  constexpr int NT = HO / 16;
  constexpr int LDW = HO + 4;
  constexpr int LDA = KC + 4;

  __shared__ float Wl[KC * LDW];
  __shared__ float inl[BM * LDA];

  const int tid = threadIdx.x;
  const int tr = tid >> 4;
  const int tc = tid & 15;
  const int row0 = blockIdx.x * BM;
  const int r0 = tr * MT;
  const int c0 = tc * NT;

  float acc[MT][NT];
#pragma unroll
  for (int i = 0; i < MT; ++i)
#pragma unroll
    for (int j = 0; j < NT; ++j) acc[i][j] = BIAS ? bias[c0 + j] : 0.f;

  for (int cc = 0; cc < K / KC; ++cc) {
    const int k0 = cc * KC;
    if (cc) __syncthreads();
    for (int idx = tid; idx < HO * (KC / 4); idx += 256) {
      int h = idx >> 4;
      int qq = idx & 15;
      float4 w = *(const float4*)(W + (size_t)h * K + k0 + qq * 4);
      Wl[(qq * 4 + 0) * LDW + h] = w.x;
      Wl[(qq * 4 + 1) * LDW + h] = w.y;
      Wl[(qq * 4 + 2) * LDW + h] = w.z;
      Wl[(qq * 4 + 3) * LDW + h] = w.w;
    }
    for (int idx = tid; idx < BM * (KC / 4); idx += 256) {
      int r = idx >> 4;
      int qq = idx & 15;
      int n = row0 + r;
      int kg = k0 + qq * 4;
      float4 v = make_float4(0.f, 0.f, 0.f, 0.f);
      if (n < nrows) {
        if constexpr (KA == K) {
          v = *(const float4*)(inA + (size_t)n * K + kg);
        } else {
          if (k0 < KA) v = *(const float4*)(inA + (size_t)n * KA + kg);
          else         v = *(const float4*)(inB + (size_t)n * (K - KA) + kg - KA);
        }
      }
      if constexpr (PRE) {
        v.x = fmaxf(v.x * preA[kg + 0] + preB[kg + 0], 0.f);
        v.y = fmaxf(v.y * preA[kg + 1] + preB[kg + 1], 0.f);
        v.z = fmaxf(v.z * preA[kg + 2] + preB[kg + 2], 0.f);
        v.w = fmaxf(v.w * preA[kg + 3] + preB[kg + 3], 0.f);
      }
      *(float4*)(inl + r * LDA + qq * 4) = v;
    }
    __syncthreads();
#pragma unroll 8
    for (int k = 0; k < KC; ++k) {
      float a[MT];
#pragma unroll
      for (int i = 0; i < MT; ++i) a[i] = inl[(r0 + i) * LDA + k];
      float4 b0 = *(const float4*)(Wl + k * LDW + c0);
#pragma unroll
      for (int i = 0; i < MT; ++i) {
        acc[i][0] = fmaf(a[i], b0.x, acc[i][0]);
        acc[i][1] = fmaf(a[i], b0.y, acc[i][1]);
        acc[i][2] = fmaf(a[i], b0.z, acc[i][2]);
        acc[i][3] = fmaf(a[i], b0.w, acc[i][3]);
      }
      if constexpr (NT == 8) {
        float4 b1 = *(const float4*)(Wl + k * LDW + c0 + 4);
#pragma unroll
        for (int i = 0; i < MT; ++i) {
          acc[i][4] = fmaf(a[i], b1.x, acc[i][4]);
          acc[i][5] = fmaf(a[i], b1.y, acc[i][5]);
          acc[i][6] = fmaf(a[i], b1.z, acc[i][6]);
          acc[i][7] = fmaf(a[i], b1.w, acc[i][7]);
        }
      }
    }
  }
  float dv[DOTM == 1 ? NT : 1];
  if constexpr (DOTM == 1) {
#pragma unroll
    for (int j = 0; j < NT; ++j) dv[j] = dvec[c0 + j];
  }
#pragma unroll
  for (int i = 0; i < MT; ++i) {
    int n = row0 + r0 + i;
    if constexpr (RELUOUT) {
#pragma unroll
      for (int j = 0; j < NT; ++j) acc[i][j] = fmaxf(acc[i][j], 0.f);
    }
    if (n < nrows) {
      float4 o0 = make_float4(acc[i][0], acc[i][1], acc[i][2], acc[i][3]);
      *(float4*)(out + (size_t)n * HO + c0) = o0;
      if constexpr (NT == 8) {
        float4 o1 = make_float4(acc[i][4], acc[i][5], acc[i][6], acc[i][7]);
        *(float4*)(out + (size_t)n * HO + c0 + 4) = o1;
      }
      if constexpr (OUT16 && NT == 8) {
        uint4 pk;
        pk.x = bf16rn(acc[i][0]) | (bf16rn(acc[i][1]) << 16);
        pk.y = bf16rn(acc[i][2]) | (bf16rn(acc[i][3]) << 16);
        pk.z = bf16rn(acc[i][4]) | (bf16rn(acc[i][5]) << 16);
        pk.w = bf16rn(acc[i][6]) | (bf16rn(acc[i][7]) << 16);
        *(uint4*)(out16 + (size_t)n * 64 + tc * 4) = pk;
      }
    }
    if constexpr (DOTM != 0) {
      float p = 0.f;
#pragma unroll
      for (int j = 0; j < NT; ++j)
        p = fmaf(acc[i][j], (DOTM == 1) ? dv[j] : acc[i][j], p);
      p += __shfl_xor(p, 1);
      p += __shfl_xor(p, 2);
      p += __shfl_xor(p, 4);
      p += __shfl_xor(p, 8);
      if (tc == 0 && n < nrows) dout[n] = (DOTM == 1) ? __expf(p) : p;
    }
  }
}

// ---------------- attention pooling (block per graph; nf in bf16) ----------------
__global__ void k_pool(const unsigned short* __restrict__ nf16, const float* __restrict__ r,
                       const int* __restrict__ gs, const int* __restrict__ ge,
                       float* __restrict__ alpha, float* __restrict__ gf) {
  int g = blockIdx.x;
  int s = gs[g], e = ge[g];
  __shared__ float red[256];
  for (int it = 0; it < 3; ++it) {
    float lm = -INFINITY;
    for (int n = s + threadIdx.x; n < e; n += 256) {
      float l = r[n];
      if (it) l *= alpha[n];
      lm = fmaxf(lm, l);
    }
    red[threadIdx.x] = lm;
    __syncthreads();
    for (int off = 128; off > 0; off >>= 1) {
      if ((int)threadIdx.x < off) red[threadIdx.x] = fmaxf(red[threadIdx.x], red[threadIdx.x + off]);
      __syncthreads();
    }
    float m = red[0];
    __syncthreads();
    float zz = 0.f;
    for (int n = s + threadIdx.x; n < e; n += 256) {
      float l = r[n];
      if (it) l *= alpha[n];
      zz += __expf(l - m);
    }
    red[threadIdx.x] = zz;
    __syncthreads();
    for (int off = 128; off > 0; off >>= 1) {
      if ((int)threadIdx.x < off) red[threadIdx.x] += red[threadIdx.x + off];
      __syncthreads();
    }
    float z = red[0];
    __syncthreads();
    float invz = 1.f / z;
    for (int n = s + threadIdx.x; n < e; n += 256) {
      float l = r[n];
      if (it) l *= alpha[n];
      alpha[n] = __expf(l - m) * invz;
    }
    __syncthreads();
  }
  int c = threadIdx.x & 127;
  int rr2 = threadIdx.x >> 7;
  float acc = 0.f;
  for (int n = s + rr2; n < e; n += 2)
    acc += alpha[n] * bf16tof(nf16[(size_t)n * HD + c]);
  red[threadIdx.x] = acc;
  __syncthreads();
  if (rr2 == 0) gf[(size_t)g * HD + c] = red[threadIdx.x] + red[threadIdx.x + 128];
}

// ---------------- BN stats / apply ----------------
__global__ void k_colstats(const float* __restrict__ y, float* __restrict__ sum,
                           float* __restrict__ sumsq, int R, int CH) {
  int c = threadIdx.x & 127;
  int rr = threadIdx.x >> 7;
  int r0 = blockIdx.x * CH;
  int r1 = min(R, r0 + CH);
  float s = 0.f, q = 0.f;
  for (int r = r0 + rr; r < r1; r += 2) {
    float v = y[(size_t)r * HD + c];
    s += v;
    q += v * v;
  }
  __shared__ float ls[256], lq[256];
  ls[threadIdx.x] = s;
  lq[threadIdx.x] = q;
  __syncthreads();
  if (rr == 0) {
    s += ls[threadIdx.x + 128];
    q += lq[threadIdx.x + 128];
    atomicAdd(&sum[c], s);
    atomicAdd(&sumsq[c], q);
  }
}

__global__ void k_bn_final(const float* __restrict__ sum, const float* __restrict__ sumsq,
                           const float* __restrict__ g, const float* __restrict__ b,
                           float* __restrict__ A, float* __restrict__ B, float R) {
  int c = threadIdx.x;
  float mu = sum[c] / R;
  float var = sumsq[c] / R - mu * mu;
  float a = g[c] * rsqrtf(var + 1e-5f);
  A[c] = a;
  B[c] = b[c] - mu * a;
}

// z16 = bf16(relu(A*y+B)) elementwise over [NN][128]
__global__ void k_bnapply(const float* __restrict__ y, const float* __restrict__ Ac,
                          const float* __restrict__ Bc, unsigned short* __restrict__ z) {
  int i = blockIdx.x * 256 + threadIdx.x;
  if (i >= NN * 16) return;
  int c = (i & 15) * 8;
  const float4* yp = (const float4*)y + (size_t)i * 2;
  float4 v0 = yp[0], v1 = yp[1];
  float4 a0 = *(const float4*)(Ac + c), a1 = *(const float4*)(Ac + c + 4);
  float4 b0 = *(const float4*)(Bc + c), b1 = *(const float4*)(Bc + c + 4);
  float r0 = fmaxf(fmaf(v0.x, a0.x, b0.x), 0.f);
  float r1 = fmaxf(fmaf(v0.y, a0.y, b0.y), 0.f);
  float r2 = fmaxf(fmaf(v0.z, a0.z, b0.z), 0.f);
  float r3 = fmaxf(fmaf(v0.w, a0.w, b0.w), 0.f);
  float r4 = fmaxf(fmaf(v1.x, a1.x, b1.x), 0.f);
  float r5 = fmaxf(fmaf(v1.y, a1.y, b1.y), 0.f);
  float r6 = fmaxf(fmaf(v1.z, a1.z, b1.z), 0.f);
  float r7 = fmaxf(fmaf(v1.w, a1.w, b1.w), 0.f);
  uint4 pk;
  pk.x = bf16rn(r0) | (bf16rn(r1) << 16);
  pk.y = bf16rn(r2) | (bf16rn(r3) << 16);
  pk.z = bf16rn(r4) | (bf16rn(r5) << 16);
  pk.w = bf16rn(r6) | (bf16rn(r7) << 16);
  *(uint4*)(z + (size_t)i * 8) = pk;
}

__global__ void k_copy4(const float4* __restrict__ a, float4* __restrict__ b, int n) {
  int i = blockIdx.x * 256 + threadIdx.x;
  if (i < n) b[i] = a[i];
}

extern "C" void kernel_launch(void* const* d_in, const int* in_sizes, int n_in,
                              void* d_out, int out_size, void* d_ws, size_t ws_size,
                              hipStream_t stream) {
  const float* x        = (const float*)d_in[0];
  const int*   ei       = (const int*)d_in[1];
  const float* edge_attr= (const float*)d_in[2];
  const int*   batch    = (const int*)d_in[3];
  const float* Wi       = (const float*)d_in[5];
  const float* bi       = (const float*)d_in[6];
  const float* gat_W    = (const float*)d_in[7];
  const float* gat_a    = (const float*)d_in[8];
  const float* nfW1     = (const float*)d_in[9];
  const float* nfb1     = (const float*)d_in[10];
  const float* nf_g     = (const float*)d_in[11];
  const float* nf_b     = (const float*)d_in[12];
  const float* nfW2     = (const float*)d_in[13];
  const float* nfb2     = (const float*)d_in[14];
  const float* gfW1     = (const float*)d_in[15];
  const float* gfb1     = (const float*)d_in[16];
  const float* gf_g     = (const float*)d_in[17];
  const float* gf_b     = (const float*)d_in[18];
  const float* gfW2     = (const float*)d_in[19];
  const float* gfb2     = (const float*)d_in[20];

  float* out = (float*)d_out;

  unsigned short* nf16A = (unsigned short*)d_ws;          // NN*128
  unsigned short* nf16B = nf16A + (size_t)NN * HD;
  unsigned short* agg16 = nf16B + (size_t)NN * HD;
  unsigned short* z16   = agg16 + (size_t)NN * HD;
  unsigned short* wt_gat = z16 + (size_t)NN * HD;          // 3*128*256
  unsigned short* wt_nf1 = wt_gat + 3 * 128 * 256;         // 128*128
  unsigned short* wt_nf2 = wt_nf1 + 128 * 128;             // 64*128
  float* nfA   = (float*)(wt_nf2 + 64 * 128);              // [NN][128] (y scratch)
  float* e1v   = nfA + (size_t)NN * HD;
  float* rv    = e1v + NN;
  float* alpha = rv + NN;
  float* gf    = alpha + NN;
  float* gy    = gf + (size_t)NG * HD;
  float* sums  = gy + (size_t)NG * HD;   // 512: sum,sumsq,A,B
  int* deg     = (int*)(sums + 512);
  int* row_ptr = deg + NN;
  int* csr_src = row_ptr + NN + 1;
  int* bsum    = csr_src + NE;
  int* gs      = bsum + 64;
  int* ge      = gs + NG;
  int* pcnt    = ge + NG;                // 64 counters
  int* hcnt    = pcnt + 64;              // 64 * GRPSZ = 1.6MB
  // pair lists alias nfA scratch (used strictly before nfA is written)
  uint2* pairs = (uint2*)nfA;            // 64 * PCAP * 8B = 14.7MB < 25.6MB

  const int* src  = ei;
  const int* dstp = ei + NE;

  // ---- CSR by dst: partition -> LDS histogram -> scan -> LDS-cursor scatter ----
  hipMemsetAsync(pcnt, 0, 64 * sizeof(int), stream);
  k_part<<<512, 256, 0, stream>>>(src, dstp, pairs, pcnt);
  k_hist<<<64, 256, 0, stream>>>(pairs, pcnt, hcnt);
  k_degsum<<<(NN + 255) / 256, 256, 0, stream>>>(hcnt, deg);
  int nsb = (NN + 1023) / 1024;
  k_scan_block<<<nsb, 1024, 0, stream>>>(deg, row_ptr, bsum, NN);
  k_scan_small<<<1, 1024, 0, stream>>>(bsum, nsb);
  k_scan_add<<<nsb, 1024, 0, stream>>>(row_ptr, bsum, NN);
  k_scat3<<<64, 256, 0, stream>>>(pairs, pcnt, hcnt, row_ptr, csr_src);

  // ---- graph bounds ----
  k_init_bounds<<<2, 256, 0, stream>>>(gs, ge);
  k_bounds<<<(NN + 255) / 256, 256, 0, stream>>>(batch, gs, ge);

  // ---- weights -> bf16 ----
  k_cvt<<<(3 * 128 * 256 + 255) / 256, 256, 0, stream>>>(gat_W, wt_gat, 3 * 128 * 256);
  k_cvt<<<(128 * 128 + 255) / 256, 256, 0, stream>>>(nfW1, wt_nf1, 128 * 128);
  k_cvt<<<(64 * 128 + 255) / 256, 256, 0, stream>>>(nfW2, wt_nf2, 64 * 128);

  // ---- input linear (fp32): nf16A + e1 = exp(nf . a0) ----
  k_gemm<64, 64, 128, false, false, true, true, 1><<<(NN + 63) / 64, 256, 0, stream>>>(
      x, nullptr, Wi, bi, nullptr, nullptr, nfA, NN, (unsigned*)nf16A, gat_a, e1v);

  // ---- 3 GAT layers (MFMA) ----
  unsigned short* cur = nf16A;
  unsigned short* nxt = nf16B;
  const int gemm_grid = (NN + 63) / 64;
  for (int l = 0; l < 3; ++l) {
    k_gat_agg<<<(NN + 3) / 4, 256, 0, stream>>>((const unsigned*)cur, e1v, row_ptr, csr_src, agg16);
    if (l < 2) {
      k_mfma<256, 128, 128, true, false, false, true, 1><<<gemm_grid, 256, 0, stream>>>(
          cur, agg16, wt_gat + (size_t)l * 128 * 256, nullptr,
          nullptr, nxt, gat_a + (size_t)(l + 1) * 256, e1v, NN);
    } else {
      k_mfma<256, 128, 128, true, false, false, true, 2><<<gemm_grid, 256, 0, stream>>>(
          cur, agg16, wt_gat + (size_t)l * 128 * 256, nullptr,
          nullptr, nxt, nullptr, rv, NN);
    }
    unsigned short* t = cur; cur = nxt; nxt = t;
  }

  // ---- attention pooling ----
  k_pool<<<NG, 256, 0, stream>>>(cur, rv, gs, ge, alpha, gf);

  // ---- nf head ----
  k_mfma<128, 128, 128, false, true, true, false, 0><<<gemm_grid, 256, 0, stream>>>(
      cur, nullptr, wt_nf1, nfb1, nfA, nullptr, nullptr, nullptr, NN);
  hipMemsetAsync(sums, 0, 256 * sizeof(float), stream);
  k_colstats<<<200, 256, 0, stream>>>(nfA, sums, sums + 128, NN, 250);
  k_bn_final<<<1, 128, 0, stream>>>(sums, sums + 128, nf_g, nf_b, sums + 256, sums + 384, (float)NN);
  k_bnapply<<<(NN * 16 + 255) / 256, 256, 0, stream>>>(nfA, sums + 256, sums + 384, z16);
  k_mfma<128, 128, 64, false, true, true, false, 0><<<gemm_grid, 256, 0, stream>>>(
      z16, nullptr, wt_nf2, nfb2, out, nullptr, nullptr, nullptr, NN);

  // ---- gf head (fp32, tiny) ----
  k_gemm<128, 128, 128, false, false, true, false, 0><<<(NG + 63) / 64, 256, 0, stream>>>(
      gf, nullptr, gfW1, gfb1, nullptr, nullptr, gy, NG, nullptr, nullptr, nullptr);
  hipMemsetAsync(sums, 0, 256 * sizeof(float), stream);
  k_colstats<<<4, 256, 0, stream>>>(gy, sums, sums + 128, NG, 128);
  k_bn_final<<<1, 128, 0, stream>>>(sums, sums + 128, gf_g, gf_b, sums + 256, sums + 384, (float)NG);
  k_gemm<128, 128, 128, true, false, true, false, 0><<<(NG + 63) / 64, 256, 0, stream>>>(
      gy, nullptr, gfW2, gfb2, sums + 256, sums + 384,
      out + (size_t)NN * 64 + (size_t)NE * 16, NG, nullptr, nullptr, nullptr);

  // ---- edge_attr passthrough ----
  int n4 = NE * 16 / 4;
  k_copy4<<<(n4 + 255) / 256, 256, 0, stream>>>((const float4*)edge_attr,
                                                (float4*)(out + (size_t)NN * 64), n4);
}

// Round 10
// 627.465 us; speedup vs baseline: 2.7699x; 1.0742x over previous
//
#include <hip/hip_runtime.h>

#define NN 50000
#define NE 1600000
#define NG 512
#define HD 128
#define NGRP 8
#define GRPSZ ((NN + NGRP - 1) / NGRP)   // 6250 (NN == 8*6250 exactly)
#define PCAP 28672                        // per (group,sub) capacity (E[cnt]=25000, sigma~148)

typedef __attribute__((ext_vector_type(8))) short bf16x8;
typedef __attribute__((ext_vector_type(4))) float f32x4;

static __device__ __forceinline__ unsigned bf16rn(float x) {
  unsigned b = __float_as_uint(x);
  return (b + 0x7FFFu + ((b >> 16) & 1u)) >> 16;
}
static __device__ __forceinline__ float bf16tof(unsigned short u) {
  return __uint_as_float(((unsigned)u) << 16);
}

// ---------------- edge partition: LDS-staged, coarse-grained global atomics ----------------
__global__ void __launch_bounds__(256) k_part(const int* __restrict__ src,
                                              const int* __restrict__ dst,
                                              uint2* __restrict__ pairs,
                                              int* __restrict__ pcnt) {
  __shared__ uint2 buf[8][512];
  __shared__ int lcnt[8];
  __shared__ int gbase[8];
  __shared__ int nfl[8];
  const int tid = threadIdx.x;
  const int b = blockIdx.x & 7;
  if (tid < 8) lcnt[tid] = 0;
  __syncthreads();
  const int stride = gridDim.x * 256;
  for (int base_e = blockIdx.x * 256; base_e < NE; base_e += stride) {
    int e = base_e + tid;
    bool valid = e < NE;
    if (valid) {
      int d = dst[e];
      int s = src[e];
      int g = d / GRPSZ;
      int pos = atomicAdd(&lcnt[g], 1);      // LDS atomic: cheap
      buf[g][pos] = make_uint2((unsigned)d, (unsigned)s);
    }
    __syncthreads();
    if (tid < 8) {
      int c = lcnt[tid];
      int nf = (c >= 256) ? 256 : 0;
      nfl[tid] = nf;
      gbase[tid] = nf ? atomicAdd(&pcnt[tid * 8 + b], nf) : 0;
    }
    __syncthreads();
#pragma unroll
    for (int g0 = 0; g0 < 8; ++g0) {
      if (nfl[g0]) {
        int gb = gbase[g0] + tid;
        if (gb < PCAP)
          pairs[(size_t)(g0 * 8 + b) * PCAP + gb] = buf[g0][tid];
      }
    }
    __syncthreads();
#pragma unroll
    for (int g0 = 0; g0 < 8; ++g0) {
      if (nfl[g0]) {
        int rem = lcnt[g0] - 256;            // < 256: no overlap with [256, 256+rem)
        if (tid < rem) buf[g0][tid] = buf[g0][256 + tid];
      }
    }
    __syncthreads();
    if (tid < 8 && nfl[tid]) lcnt[tid] -= 256;
    __syncthreads();
  }
  // epilogue flush
  if (tid < 8) {
    int c = lcnt[tid];
    gbase[tid] = c ? atomicAdd(&pcnt[tid * 8 + b], c) : 0;
  }
  __syncthreads();
#pragma unroll
  for (int g0 = 0; g0 < 8; ++g0) {
    int c = lcnt[g0];
    if (tid < c) {
      int gb = gbase[g0] + tid;
      if (gb < PCAP)
        pairs[(size_t)(g0 * 8 + b) * PCAP + gb] = buf[g0][tid];
    }
  }
}

// ---------------- per-list LDS histogram -> global hcnt (no global atomics) ----------------
__global__ void __launch_bounds__(256) k_hist(const uint2* __restrict__ pairs,
                                              const int* __restrict__ pcnt,
                                              int* __restrict__ hcnt) {
  __shared__ int hist[GRPSZ];
  const int b = blockIdx.x;           // 64 blocks
  const int g = b & 7, sub = b >> 3;
  const int li = g * 8 + sub;
  const int lo = g * GRPSZ;
  for (int i = threadIdx.x; i < GRPSZ; i += 256) hist[i] = 0;
  __syncthreads();
  int cnt = min(pcnt[li], PCAP);
  const uint2* lst = pairs + (size_t)li * PCAP;
  for (int i = threadIdx.x; i < cnt; i += 256)
    atomicAdd(&hist[(int)lst[i].x - lo], 1);
  __syncthreads();
  for (int i = threadIdx.x; i < GRPSZ; i += 256)
    hcnt[(size_t)li * GRPSZ + i] = hist[i];
}

// ---------------- fused: in-LDS degree scan + row_ptr write + cursor scatter ----------------
// Replaces degsum + 3 scan kernels + scat3. 64 blocks, one per (group,sub).
__global__ void __launch_bounds__(256) k_csr(const uint2* __restrict__ pairs,
                                             const int* __restrict__ pcnt,
                                             const int* __restrict__ hcnt,
                                             int* __restrict__ row_ptr,
                                             int* __restrict__ csr_src) {
  __shared__ int rp[GRPSZ];    // deg -> group-local exclusive prefix (25KB)
  __shared__ int cur[GRPSZ];   // per-sub cursor base (25KB)
  __shared__ int wsum[256];
  const int b = blockIdx.x;
  const int g = b & 7, sub = b >> 3;
  const int li = g * 8 + sub;
  const int lo = g * GRPSZ;
  // groupBase = total edges of groups < g (pcnt is exact per-(g,sub) count)
  int gbase = 0;
  for (int gg = 0; gg < g; ++gg)
#pragma unroll
    for (int ss = 0; ss < 8; ++ss) gbase += pcnt[gg * 8 + ss];
  // load deg and per-sub partial offsets
  for (int i = threadIdx.x; i < GRPSZ; i += 256) {
    int dsum = 0, before = 0;
#pragma unroll
    for (int ss = 0; ss < 8; ++ss) {
      int h = hcnt[(size_t)(g * 8 + ss) * GRPSZ + i];
      dsum += h;
      if (ss < sub) before += h;
    }
    rp[i] = dsum;
    cur[i] = before;
  }
  __syncthreads();
  // block exclusive scan of rp (chunked: 256 threads x 25 elems)
  const int CH = (GRPSZ + 255) / 256;   // 25
  int t0 = threadIdx.x * CH;
  int t1 = min(GRPSZ, t0 + CH);
  int s = 0;
  for (int i = t0; i < t1; ++i) { int v = rp[i]; rp[i] = s; s += v; }
  wsum[threadIdx.x] = s;
  __syncthreads();
  for (int off = 1; off < 256; off <<= 1) {
    int t = ((int)threadIdx.x >= off) ? wsum[threadIdx.x - off] : 0;
    __syncthreads();
    wsum[threadIdx.x] += t;
    __syncthreads();
  }
  int add = gbase + ((threadIdx.x > 0) ? wsum[threadIdx.x - 1] : 0);
  for (int i = t0; i < t1; ++i) rp[i] += add;
  __syncthreads();
  for (int i = threadIdx.x; i < GRPSZ; i += 256) {
    cur[i] += rp[i];
    if (sub == 0) row_ptr[lo + i] = rp[i];
  }
  if (sub == 0 && g == 7 && threadIdx.x == 0) row_ptr[NN] = NE;
  __syncthreads();
  // scatter (LDS cursors, plain global stores)
  int cnt = min(pcnt[li], PCAP);
  const uint2* lst = pairs + (size_t)li * PCAP;
  for (int i = threadIdx.x; i < cnt; i += 256) {
    uint2 p = lst[i];
    int pos = atomicAdd(&cur[(int)p.x - lo], 1);
    csr_src[pos] = (int)p.y;
  }
}

// ---------------- graph segment bounds (batch is sorted) ----------------
__global__ void k_init_bounds(int* __restrict__ gs, int* __restrict__ ge) {
  int g = blockIdx.x * 256 + threadIdx.x;
  if (g < NG) { gs[g] = NN; ge[g] = 0; }
}
__global__ void k_bounds(const int* __restrict__ batch, int* __restrict__ gs, int* __restrict__ ge) {
  int n = blockIdx.x * 256 + threadIdx.x;
  if (n < NN) {
    int b = batch[n];
    atomicMin(&gs[b], n);
    atomicMax(&ge[b], n + 1);
  }
}

// ---------------- fp32 -> bf16 convert (3 sources fused) ----------------
__global__ void k_cvt3(const float* __restrict__ a0, int n0,
                       const float* __restrict__ a1, int n1,
                       const float* __restrict__ a2, int n2,
                       unsigned short* __restrict__ b) {
  int i = blockIdx.x * 256 + threadIdx.x;
  if (i >= n0 + n1 + n2) return;
  float v = (i < n0) ? a0[i] : (i < n0 + n1) ? a1[i - n0] : a2[i - n0 - n1];
  b[i] = (unsigned short)bf16rn(v);
}

// ---------------- GAT softmax + aggregate: 8 edges/trip, 32B/lane, pipelined ----------------
// lane = (q=lane>>3 edge slot, c=lane&7 32B row chunk). 4KB/wave in flight.
__global__ void k_gat_agg(const uint4* __restrict__ nf16u4, const float* __restrict__ e1,
                          const int* __restrict__ row_ptr, const int* __restrict__ csr_src,
                          unsigned short* __restrict__ agg16) {
  int node = blockIdx.x * 4 + (threadIdx.x >> 6);
  int lane = threadIdx.x & 63;
  if (node >= NN) return;
  int s = row_ptr[node], e = row_ptr[node + 1];
  const int q = lane >> 3;
  const int c = lane & 7;

  float acc[16];
#pragma unroll
  for (int i = 0; i < 16; ++i) acc[i] = 0.f;
  float zloc = 0.f;

  int jj = s + q;
  bool v0 = jj < e;
  int sc = v0 ? csr_src[jj] : 0;
  float w = v0 ? e1[sc] : 0.f;
  uint4 u0 = nf16u4[(size_t)sc * 16 + c * 2];
  uint4 u1 = nf16u4[(size_t)sc * 16 + c * 2 + 1];

  for (int j = s; j < e; j += 8) {
    int jn = j + 8 + q;
    bool vn = jn < e;
    int scn = vn ? csr_src[jn] : 0;
    float wn = vn ? e1[scn] : 0.f;
    uint4 un0 = nf16u4[(size_t)scn * 16 + c * 2];
    uint4 un1 = nf16u4[(size_t)scn * 16 + c * 2 + 1];
    zloc += w;
    acc[0]  = fmaf(w, __uint_as_float(u0.x << 16), acc[0]);
    acc[1]  = fmaf(w, __uint_as_float(u0.x & 0xFFFF0000u), acc[1]);
    acc[2]  = fmaf(w, __uint_as_float(u0.y << 16), acc[2]);
    acc[3]  = fmaf(w, __uint_as_float(u0.y & 0xFFFF0000u), acc[3]);
    acc[4]  = fmaf(w, __uint_as_float(u0.z << 16), acc[4]);
    acc[5]  = fmaf(w, __uint_as_float(u0.z & 0xFFFF0000u), acc[5]);
    acc[6]  = fmaf(w, __uint_as_float(u0.w << 16), acc[6]);
    acc[7]  = fmaf(w, __uint_as_float(u0.w & 0xFFFF0000u), acc[7]);
    acc[8]  = fmaf(w, __uint_as_float(u1.x << 16), acc[8]);
    acc[9]  = fmaf(w, __uint_as_float(u1.x & 0xFFFF0000u), acc[9]);
    acc[10] = fmaf(w, __uint_as_float(u1.y << 16), acc[10]);
    acc[11] = fmaf(w, __uint_as_float(u1.y & 0xFFFF0000u), acc[11]);
    acc[12] = fmaf(w, __uint_as_float(u1.z << 16), acc[12]);
    acc[13] = fmaf(w, __uint_as_float(u1.z & 0xFFFF0000u), acc[13]);
    acc[14] = fmaf(w, __uint_as_float(u1.w << 16), acc[14]);
    acc[15] = fmaf(w, __uint_as_float(u1.w & 0xFFFF0000u), acc[15]);
    sc = scn; w = wn; u0 = un0; u1 = un1;
  }

  // sum across the 8 edge slots (lane bits 3,4,5)
  zloc += __shfl_xor(zloc, 8);
  zloc += __shfl_xor(zloc, 16);
  zloc += __shfl_xor(zloc, 32);
  float inv = (zloc > 0.f) ? 1.f / zloc : 0.f;
#pragma unroll
  for (int i = 0; i < 16; ++i) {
    acc[i] += __shfl_xor(acc[i], 8);
    acc[i] += __shfl_xor(acc[i], 16);
    acc[i] += __shfl_xor(acc[i], 32);
    acc[i] *= inv;
  }
  if (q == 0) {
    uint4 p0, p1;
    p0.x = bf16rn(acc[0])  | (bf16rn(acc[1])  << 16);
    p0.y = bf16rn(acc[2])  | (bf16rn(acc[3])  << 16);
    p0.z = bf16rn(acc[4])  | (bf16rn(acc[5])  << 16);
    p0.w = bf16rn(acc[6])  | (bf16rn(acc[7])  << 16);
    p1.x = bf16rn(acc[8])  | (bf16rn(acc[9])  << 16);
    p1.y = bf16rn(acc[10]) | (bf16rn(acc[11]) << 16);
    p1.z = bf16rn(acc[12]) | (bf16rn(acc[13]) << 16);
    p1.w = bf16rn(acc[14]) | (bf16rn(acc[15]) << 16);
    uint4* dst = (uint4*)(agg16 + (size_t)node * HD + c * 16);
    dst[0] = p0;
    dst[1] = p1;
  }
}

// ---------------- MFMA bf16 GEMM (direct-from-global fragments) ----------------
template <int K, int KA, int HO, bool RELUOUT, bool BIAS, bool OUTF32, bool OUT16, int DOTM>
__global__ void __launch_bounds__(256) k_mfma(
    const unsigned short* __restrict__ A1, const unsigned short* __restrict__ A2,
    const unsigned short* __restrict__ W16, const float* __restrict__ bias,
    float* __restrict__ outf, unsigned short* __restrict__ out16,
    const float* __restrict__ dvec, float* __restrict__ dout, int nrows) {
  constexpr int NT = HO / 16;
  const int l = threadIdx.x & 63;
  const int w = threadIdx.x >> 6;
  const int lr = l & 15;
  const int q = l >> 4;
  const int row0 = blockIdx.x * 64 + w * 16;
  const int arow = min(row0 + lr, nrows - 1);
  const unsigned short* pa1 = A1 + (size_t)arow * KA;
  const unsigned short* pa2 = (KA < K) ? (A2 + (size_t)arow * (K - KA)) : nullptr;

  f32x4 acc[NT];
#pragma unroll
  for (int t = 0; t < NT; ++t) acc[t] = (f32x4){0.f, 0.f, 0.f, 0.f};

#pragma unroll
  for (int s = 0; s < K / 32; ++s) {
    const int kg = s * 32 + q * 8;
    bf16x8 af;
    if constexpr (KA == K) {
      af = *(const bf16x8*)(pa1 + kg);
    } else {
      af = (s * 32 < KA) ? *(const bf16x8*)(pa1 + kg)
                         : *(const bf16x8*)(pa2 + (kg - KA));
    }
#pragma unroll
    for (int t = 0; t < NT; ++t) {
      bf16x8 bfr = *(const bf16x8*)(W16 + (size_t)(t * 16 + lr) * K + kg);
      acc[t] = __builtin_amdgcn_mfma_f32_16x16x32_bf16(af, bfr, acc[t], 0, 0, 0);
    }
  }

  float bv[BIAS ? NT : 1];
  if constexpr (BIAS) {
#pragma unroll
    for (int t = 0; t < NT; ++t) bv[t] = bias[t * 16 + lr];
  }
  float dv[DOTM == 1 ? NT : 1];
  if constexpr (DOTM == 1) {
#pragma unroll
    for (int t = 0; t < NT; ++t) dv[t] = dvec[t * 16 + lr];
  }
  float p[4] = {0.f, 0.f, 0.f, 0.f};
#pragma unroll
  for (int j = 0; j < 4; ++j) {
    int n = row0 + q * 4 + j;
    bool ok = n < nrows;
#pragma unroll
    for (int t = 0; t < NT; ++t) {
      float v = acc[t][j];
      if constexpr (BIAS) v += bv[t];
      if constexpr (RELUOUT) v = fmaxf(v, 0.f);
      if (ok) {
        if constexpr (OUTF32) outf[(size_t)n * HO + t * 16 + lr] = v;
        if constexpr (OUT16) out16[(size_t)n * HO + t * 16 + lr] = (unsigned short)bf16rn(v);
      }
      if constexpr (DOTM == 1) p[j] = fmaf(v, dv[t], p[j]);
      if constexpr (DOTM == 2) p[j] = fmaf(v, v, p[j]);
    }
  }
  if constexpr (DOTM != 0) {
#pragma unroll
    for (int j = 0; j < 4; ++j) {
      p[j] += __shfl_xor(p[j], 1);
      p[j] += __shfl_xor(p[j], 2);
      p[j] += __shfl_xor(p[j], 4);
      p[j] += __shfl_xor(p[j], 8);
    }
    if (lr == 0) {
#pragma unroll
      for (int j = 0; j < 4; ++j) {
        int n = row0 + q * 4 + j;
        if (n < nrows) dout[n] = (DOTM == 1) ? __expf(p[j]) : p[j];
      }
    }
  }
}

// ---------------- fp32 register-tiled GEMM (input + gf head) ----------------
template <int K, int KA, int HO, bool PRE, bool RELUOUT, bool BIAS, bool OUT16, int DOTM>
__global__ void __launch_bounds__(256) k_gemm(
    const float* __restrict__ inA, const float* __restrict__ inB,
    const float* __restrict__ W, const float* __restrict__ bias,
    const float* __restrict__ preA, const float* __restrict__ preB,
    float* __restrict__ out, int nrows,
    unsigned* __restrict__ out16, const float* __restrict__ dvec,
    float* __restrict__ dout) {
  constexpr int KC = 64;
  constexpr int BM = 64;
  constexpr int MT = 4;
  constexpr int NT = HO / 16;
  constexpr int LDW = HO + 4;
  constexpr int LDA = KC + 4;

  __shared__ float Wl[KC * LDW];
  __shared__ float inl[BM * LDA];

  const int tid = threadIdx.x;
  const int tr = tid >> 4;
  const int tc = tid & 15;
  const int row0 = blockIdx.x * BM;
  const int r0 = tr * MT;
  const int c0 = tc * NT;

  float acc[MT][NT];
#pragma unroll
  for (int i = 0; i < MT; ++i)
#pragma unroll
    for (int j = 0; j < NT; ++j) acc[i][j] = BIAS ? bias[c0 + j] : 0.f;

  for (int cc = 0; cc < K / KC; ++cc) {
    const int k0 = cc * KC;
    if (cc) __syncthreads();
    for (int idx = tid; idx < HO * (KC / 4); idx += 256) {
      int h = idx >> 4;
      int qq = idx & 15;
      float4 w = *(const float4*)(W + (size_t)h * K + k0 + qq * 4);
      Wl[(qq * 4 + 0) * LDW + h] = w.x;
      Wl[(qq * 4 + 1) * LDW + h] = w.y;
      Wl[(qq * 4 + 2) * LDW + h] = w.z;
      Wl[(qq * 4 + 3) * LDW + h] = w.w;
    }
    for (int idx = tid; idx < BM * (KC / 4); idx += 256) {
      int r = idx >> 4;
      int qq = idx & 15;
      int n = row0 + r;
      int kg = k0 + qq * 4;
      float4 v = make_float4(0.f, 0.f, 0.f, 0.f);
      if (n < nrows) {
        if constexpr (KA == K) {
          v = *(const float4*)(inA + (size_t)n * K + kg);
        } else {
          if (k0 < KA) v = *(const float4*)(inA + (size_t)n * KA + kg);
          else         v = *(const float4*)(inB + (size_t)n * (K - KA) + kg - KA);
        }
      }
      if constexpr (PRE) {
        v.x = fmaxf(v.x * preA[kg + 0] + preB[kg + 0], 0.f);
        v.y = fmaxf(v.y * preA[kg + 1] + preB[kg + 1], 0.f);
        v.z = fmaxf(v.z * preA[kg + 2] + preB[kg + 2], 0.f);
        v.w = fmaxf(v.w * preA[kg + 3] + preB[kg + 3], 0.f);
      }
      *(float4*)(inl + r * LDA + qq * 4) = v;
    }
    __syncthreads();
#pragma unroll 8
    for (int k = 0; k < KC; ++k) {
      float a[MT];
#pragma unroll
      for (int i = 0; i < MT; ++i) a[i] = inl[(r0 + i) * LDA + k];
      float4 b0 = *(const float4*)(Wl + k * LDW + c0);
#pragma unroll
      for (int i = 0; i < MT; ++i) {
        acc[i][0] = fmaf(a[i], b0.x, acc[i][0]);
        acc[i][1] = fmaf(a[i], b0.y, acc[i][1]);
        acc[i][2] = fmaf(a[i], b0.z, acc[i][2]);
        acc[i][3] = fmaf(a[i], b0.w, acc[i][3]);
      }
      if constexpr (NT == 8) {
        float4 b1 = *(const float4*)(Wl + k * LDW + c0 + 4);
#pragma unroll
        for (int i = 0; i < MT; ++i) {
          acc[i][4] = fmaf(a[i], b1.x, acc[i][4]);
          acc[i][5] = fmaf(a[i], b1.y, acc[i][5]);
          acc[i][6] = fmaf(a[i], b1.z, acc[i][6]);
          acc[i][7] = fmaf(a[i], b1.w, acc[i][7]);
        }
      }
    }
  }
  float dv[DOTM == 1 ? NT : 1];
  if constexpr (DOTM == 1) {
#pragma unroll
    for (int j = 0; j < NT; ++j) dv[j] = dvec[c0 + j];
  }
#pragma unroll
  for (int i = 0; i < MT; ++i) {
    int n = row0 + r0 + i;
    if constexpr (RELUOUT) {
#pragma unroll
      for (int j = 0; j < NT; ++j) acc[i][j] = fmaxf(acc[i][j], 0.f);
    }
    if (n < nrows) {
      float4 o0 = make_float4(acc[i][0], acc[i][1], acc[i][2], acc[i][3]);
      *(float4*)(out + (size_t)n * HO + c0) = o0;
      if constexpr (NT == 8) {
        float4 o1 = make_float4(acc[i][4], acc[i][5], acc[i][6], acc[i][7]);
        *(float4*)(out + (size_t)n * HO + c0 + 4) = o1;
      }
      if constexpr (OUT16 && NT == 8) {
        uint4 pk;
        pk.x = bf16rn(acc[i][0]) | (bf16rn(acc[i][1]) << 16);
        pk.y = bf16rn(acc[i][2]) | (bf16rn(acc[i][3]) << 16);
        pk.z = bf16rn(acc[i][4]) | (bf16rn(acc[i][5]) << 16);
        pk.w = bf16rn(acc[i][6]) | (bf16rn(acc[i][7]) << 16);
        *(uint4*)(out16 + (size_t)n * 64 + tc * 4) = pk;
      }
    }
    if constexpr (DOTM != 0) {
      float p = 0.f;
#pragma unroll
      for (int j = 0; j < NT; ++j)
        p = fmaf(acc[i][j], (DOTM == 1) ? dv[j] : acc[i][j], p);
      p += __shfl_xor(p, 1);
      p += __shfl_xor(p, 2);
      p += __shfl_xor(p, 4);
      p += __shfl_xor(p, 8);
      if (tc == 0 && n < nrows) dout[n] = (DOTM == 1) ? __expf(p) : p;
    }
  }
}

// ---------------- attention pooling (block per graph; nf in bf16) ----------------
__global__ void k_pool(const unsigned short* __restrict__ nf16, const float* __restrict__ r,
                       const int* __restrict__ gs, const int* __restrict__ ge,
                       float* __restrict__ alpha, float* __restrict__ gf) {
  int g = blockIdx.x;
  int s = gs[g], e = ge[g];
  __shared__ float red[256];
  for (int it = 0; it < 3; ++it) {
    float lm = -INFINITY;
    for (int n = s + threadIdx.x; n < e; n += 256) {
      float l = r[n];
      if (it) l *= alpha[n];
      lm = fmaxf(lm, l);
    }
    red[threadIdx.x] = lm;
    __syncthreads();
    for (int off = 128; off > 0; off >>= 1) {
      if ((int)threadIdx.x < off) red[threadIdx.x] = fmaxf(red[threadIdx.x], red[threadIdx.x + off]);
      __syncthreads();
    }
    float m = red[0];
    __syncthreads();
    float zz = 0.f;
    for (int n = s + threadIdx.x; n < e; n += 256) {
      float l = r[n];
      if (it) l *= alpha[n];
      zz += __expf(l - m);
    }
    red[threadIdx.x] = zz;
    __syncthreads();
    for (int off = 128; off > 0; off >>= 1) {
      if ((int)threadIdx.x < off) red[threadIdx.x] += red[threadIdx.x + off];
      __syncthreads();
    }
    float z = red[0];
    __syncthreads();
    float invz = 1.f / z;
    for (int n = s + threadIdx.x; n < e; n += 256) {
      float l = r[n];
      if (it) l *= alpha[n];
      alpha[n] = __expf(l - m) * invz;
    }
    __syncthreads();
  }
  int c = threadIdx.x & 127;
  int rr2 = threadIdx.x >> 7;
  float acc = 0.f;
  for (int n = s + rr2; n < e; n += 2)
    acc += alpha[n] * bf16tof(nf16[(size_t)n * HD + c]);
  red[threadIdx.x] = acc;
  __syncthreads();
  if (rr2 == 0) gf[(size_t)g * HD + c] = red[threadIdx.x] + red[threadIdx.x + 128];
}

// ---------------- BN stats / apply ----------------
__global__ void k_colstats(const float* __restrict__ y, float* __restrict__ sum,
                           float* __restrict__ sumsq, int R, int CH) {
  int c = threadIdx.x & 127;
  int rr = threadIdx.x >> 7;
  int r0 = blockIdx.x * CH;
  int r1 = min(R, r0 + CH);
  float s = 0.f, q = 0.f;
  for (int r = r0 + rr; r < r1; r += 2) {
    float v = y[(size_t)r * HD + c];
    s += v;
    q += v * v;
  }
  __shared__ float ls[256], lq[256];
  ls[threadIdx.x] = s;
  lq[threadIdx.x] = q;
  __syncthreads();
  if (rr == 0) {
    s += ls[threadIdx.x + 128];
    q += lq[threadIdx.x + 128];
    atomicAdd(&sum[c], s);
    atomicAdd(&sumsq[c], q);
  }
}

__global__ void k_bn_final(const float* __restrict__ sum, const float* __restrict__ sumsq,
                           const float* __restrict__ g, const float* __restrict__ b,
                           float* __restrict__ A, float* __restrict__ B, float R) {
  int c = threadIdx.x;
  float mu = sum[c] / R;
  float var = sumsq[c] / R - mu * mu;
  float a = g[c] * rsqrtf(var + 1e-5f);
  A[c] = a;
  B[c] = b[c] - mu * a;
}

// z16 = bf16(relu(A*y+B)) elementwise over [NN][128]
__global__ void k_bnapply(const float* __restrict__ y, const float* __restrict__ Ac,
                          const float* __restrict__ Bc, unsigned short* __restrict__ z) {
  int i = blockIdx.x * 256 + threadIdx.x;
  if (i >= NN * 16) return;
  int c = (i & 15) * 8;
  const float4* yp = (const float4*)y + (size_t)i * 2;
  float4 v0 = yp[0], v1 = yp[1];
  float4 a0 = *(const float4*)(Ac + c), a1 = *(const float4*)(Ac + c + 4);
  float4 b0 = *(const float4*)(Bc + c), b1 = *(const float4*)(Bc + c + 4);
  float r0 = fmaxf(fmaf(v0.x, a0.x, b0.x), 0.f);
  float r1 = fmaxf(fmaf(v0.y, a0.y, b0.y), 0.f);
  float r2 = fmaxf(fmaf(v0.z, a0.z, b0.z), 0.f);
  float r3 = fmaxf(fmaf(v0.w, a0.w, b0.w), 0.f);
  float r4 = fmaxf(fmaf(v1.x, a1.x, b1.x), 0.f);
  float r5 = fmaxf(fmaf(v1.y, a1.y, b1.y), 0.f);
  float r6 = fmaxf(fmaf(v1.z, a1.z, b1.z), 0.f);
  float r7 = fmaxf(fmaf(v1.w, a1.w, b1.w), 0.f);
  uint4 pk;
  pk.x = bf16rn(r0) | (bf16rn(r1) << 16);
  pk.y = bf16rn(r2) | (bf16rn(r3) << 16);
  pk.z = bf16rn(r4) | (bf16rn(r5) << 16);
  pk.w = bf16rn(r6) | (bf16rn(r7) << 16);
  *(uint4*)(z + (size_t)i * 8) = pk;
}

__global__ void k_copy4(const float4* __restrict__ a, float4* __restrict__ b, int n) {
  int i = blockIdx.x * 256 + threadIdx.x;
  if (i < n) b[i] = a[i];
}

extern "C" void kernel_launch(void* const* d_in, const int* in_sizes, int n_in,
                              void* d_out, int out_size, void* d_ws, size_t ws_size,
                              hipStream_t stream) {
  const float* x        = (const float*)d_in[0];
  const int*   ei       = (const int*)d_in[1];
  const float* edge_attr= (const float*)d_in[2];
  const int*   batch    = (const int*)d_in[3];
  const float* Wi       = (const float*)d_in[5];
  const float* bi       = (const float*)d_in[6];
  const float* gat_W    = (const float*)d_in[7];
  const float* gat_a    = (const float*)d_in[8];
  const float* nfW1     = (const float*)d_in[9];
  const float* nfb1     = (const float*)d_in[10];
  const float* nf_g     = (const float*)d_in[11];
  const float* nf_b     = (const float*)d_in[12];
  const float* nfW2     = (const float*)d_in[13];
  const float* nfb2     = (const float*)d_in[14];
  const float* gfW1     = (const float*)d_in[15];
  const float* gfb1     = (const float*)d_in[16];
  const float* gf_g     = (const float*)d_in[17];
  const float* gf_b     = (const float*)d_in[18];
  const float* gfW2     = (const float*)d_in[19];
  const float* gfb2     = (const float*)d_in[20];

  float* out = (float*)d_out;

  unsigned short* nf16A = (unsigned short*)d_ws;          // NN*128
  unsigned short* nf16B = nf16A + (size_t)NN * HD;
  unsigned short* agg16 = nf16B + (size_t)NN * HD;
  unsigned short* z16   = agg16 + (size_t)NN * HD;
  unsigned short* wt_gat = z16 + (size_t)NN * HD;          // 3*128*256
  unsigned short* wt_nf1 = wt_gat + 3 * 128 * 256;         // 128*128
  unsigned short* wt_nf2 = wt_nf1 + 128 * 128;             // 64*128
  float* nfA   = (float*)(wt_nf2 + 64 * 128);              // [NN][128] (y scratch)
  float* e1v   = nfA + (size_t)NN * HD;
  float* rv    = e1v + NN;
  float* alpha = rv + NN;
  float* gf    = alpha + NN;
  float* gy    = gf + (size_t)NG * HD;
  int*   pcnt  = (int*)(gy + (size_t)NG * HD);  // 64 (zeroed)
  float* sums  = (float*)(pcnt + 64);           // 256 NF stats (zeroed)
  float* sums2 = sums + 256;                    // 256 GF stats (zeroed)
  float* bnAB  = sums2 + 256;                   // 256: A,B (written by bn_final)
  int* row_ptr = (int*)(bnAB + 256);            // NN+1
  int* csr_src = row_ptr + NN + 1;              // NE
  int* gs      = csr_src + NE;
  int* ge      = gs + NG;
  int* hcnt    = ge + NG;                       // 64 * GRPSZ
  // pair lists alias nfA scratch (used strictly before nfA is written)
  uint2* pairs = (uint2*)nfA;                   // 64 * PCAP * 8B = 14.7MB < 25.6MB

  const int* src  = ei;
  const int* dstp = ei + NE;

  // ---- one merged memset: pcnt + both BN stat regions ----
  hipMemsetAsync(pcnt, 0, (64 + 512) * sizeof(int), stream);

  // ---- CSR by dst: partition -> LDS histogram -> fused scan+scatter ----
  k_part<<<512, 256, 0, stream>>>(src, dstp, pairs, pcnt);
  k_hist<<<64, 256, 0, stream>>>(pairs, pcnt, hcnt);
  k_csr<<<64, 256, 0, stream>>>(pairs, pcnt, hcnt, row_ptr, csr_src);

  // ---- graph bounds ----
  k_init_bounds<<<2, 256, 0, stream>>>(gs, ge);
  k_bounds<<<(NN + 255) / 256, 256, 0, stream>>>(batch, gs, ge);

  // ---- weights -> bf16 (one kernel; wt_gat/wt_nf1/wt_nf2 contiguous) ----
  k_cvt3<<<(3 * 128 * 256 + 128 * 128 + 64 * 128 + 255) / 256, 256, 0, stream>>>(
      gat_W, 3 * 128 * 256, nfW1, 128 * 128, nfW2, 64 * 128, wt_gat);

  // ---- input linear (fp32): nf16A + e1 = exp(nf . a0) ----
  k_gemm<64, 64, 128, false, false, true, true, 1><<<(NN + 63) / 64, 256, 0, stream>>>(
      x, nullptr, Wi, bi, nullptr, nullptr, nfA, NN, (unsigned*)nf16A, gat_a, e1v);

  // ---- 3 GAT layers (MFMA) ----
  unsigned short* cur = nf16A;
  unsigned short* nxt = nf16B;
  const int gemm_grid = (NN + 63) / 64;
  for (int l = 0; l < 3; ++l) {
    k_gat_agg<<<(NN + 3) / 4, 256, 0, stream>>>((const uint4*)cur, e1v, row_ptr, csr_src, agg16);
    if (l < 2) {
      k_mfma<256, 128, 128, true, false, false, true, 1><<<gemm_grid, 256, 0, stream>>>(
          cur, agg16, wt_gat + (size_t)l * 128 * 256, nullptr,
          nullptr, nxt, gat_a + (size_t)(l + 1) * 256, e1v, NN);
    } else {
      k_mfma<256, 128, 128, true, false, false, true, 2><<<gemm_grid, 256, 0, stream>>>(
          cur, agg16, wt_gat + (size_t)l * 128 * 256, nullptr,
          nullptr, nxt, nullptr, rv, NN);
    }
    unsigned short* t = cur; cur = nxt; nxt = t;
  }

  // ---- attention pooling ----
  k_pool<<<NG, 256, 0, stream>>>(cur, rv, gs, ge, alpha, gf);

  // ---- nf head ----
  k_mfma<128, 128, 128, false, true, true, false, 0><<<gemm_grid, 256, 0, stream>>>(
      cur, nullptr, wt_nf1, nfb1, nfA, nullptr, nullptr, nullptr, NN);
  k_colstats<<<200, 256, 0, stream>>>(nfA, sums, sums + 128, NN, 250);
  k_bn_final<<<1, 128, 0, stream>>>(sums, sums + 128, nf_g, nf_b, bnAB, bnAB + 128, (float)NN);
  k_bnapply<<<(NN * 16 + 255) / 256, 256, 0, stream>>>(nfA, bnAB, bnAB + 128, z16);
  k_mfma<128, 128, 64, false, true, true, false, 0><<<gemm_grid, 256, 0, stream>>>(
      z16, nullptr, wt_nf2, nfb2, out, nullptr, nullptr, nullptr, NN);

  // ---- gf head (fp32, tiny) ----
  k_gemm<128, 128, 128, false, false, true, false, 0><<<(NG + 63) / 64, 256, 0, stream>>>(
      gf, nullptr, gfW1, gfb1, nullptr, nullptr, gy, NG, nullptr, nullptr, nullptr);
  k_colstats<<<4, 256, 0, stream>>>(gy, sums2, sums2 + 128, NG, 128);
  k_bn_final<<<1, 128, 0, stream>>>(sums2, sums2 + 128, gf_g, gf_b, bnAB, bnAB + 128, (float)NG);
  k_gemm<128, 128, 128, true, false, true, false, 0><<<(NG + 63) / 64, 256, 0, stream>>>(
      gy, nullptr, gfW2, gfb2, bnAB, bnAB + 128,
      out + (size_t)NN * 64 + (size_t)NE * 16, NG, nullptr, nullptr, nullptr);

  // ---- edge_attr passthrough ----
  int n4 = NE * 16 / 4;
  k_copy4<<<(n4 + 255) / 256, 256, 0, stream>>>((const float4*)edge_attr,
                                                (float4*)(out + (size_t)NN * 64), n4);
}